// Round 9
// baseline (5810.780 us; speedup 1.0000x reference)
//
#include <hip/hip_runtime.h>
#include <math.h>

#define NUM_CODE 256
#define CODE_DIM 128
#define HALF_DIM 64
#define N_LAYERS 5
#define TT 8192
#define MTOK 131072
#define MARGIN 4e-5f

#define QOFF   0ull
#define IOFF   83886080ull              // 16*128*8192*5
#define PPLOFF 84541440ull
#define LOSSOFF 84541445ull

// ws: [0,5120) u32 cnt[5][256]; [5120,5160) double loss[5]; [5160,10280) float ee2[5][256]
//
// Numeric model (CONFIRMED r6, tiered machinery VALIDATED r8): dot_c / ee2_c =
// numpy pairwise-8 mul/add trees; dist = fl(fl(rr2+ee2_c) - fl(2*dot_c));
// argmin first-min; residual fl32 subtract.
// r9 structure: 2 threads/token splitting CODES by parity (each holds full
// r[128]); fast fmaf scan, thread-local tiered exact, one margin-aware
// pair-merge per layer (exact re-eval on near-tie, symmetric first-min).

__global__ __launch_bounds__(256) void rvq_init_kernel(
        const float* __restrict__ emb,
        unsigned int* __restrict__ cnt,
        double* __restrict__ lossws,
        float* __restrict__ ee2)
{
    int g = blockIdx.x * 256 + threadIdx.x;
    if (g < N_LAYERS) lossws[g] = 0.0;
    if (g < N_LAYERS * NUM_CODE) {
        cnt[g] = 0u;
        const float* e = emb + (size_t)g * CODE_DIM;
        float s[8];
        #pragma unroll
        for (int j = 0; j < 8; ++j) s[j] = __fmul_rn(e[j], e[j]);
        #pragma unroll
        for (int i = 8; i < CODE_DIM; i += 8) {
            #pragma unroll
            for (int j = 0; j < 8; ++j)
                s[j] = __fadd_rn(s[j], __fmul_rn(e[i + j], e[i + j]));
        }
        ee2[g] = __fadd_rn(
            __fadd_rn(__fadd_rn(s[0], s[1]), __fadd_rn(s[2], s[3])),
            __fadd_rn(__fadd_rn(s[4], s[5]), __fadd_rn(s[6], s[7])));
    }
}

// Bitwise-exact reference dist for one code, computed entirely in-thread
// (thread holds full r[128]): numpy pairwise-8 mul/add tree.
__device__ __forceinline__ float exact_di(
        const float* __restrict__ row, const float r[CODE_DIM], float t1)
{
    float s[8];
    const float4* rv = reinterpret_cast<const float4*>(row);
    #pragma unroll
    for (int i = 0; i < 16; ++i) {
        float4 e0 = rv[2 * i];
        float4 e1 = rv[2 * i + 1];
        float p0 = __fmul_rn(r[8*i+0], e0.x);
        float p1 = __fmul_rn(r[8*i+1], e0.y);
        float p2 = __fmul_rn(r[8*i+2], e0.z);
        float p3 = __fmul_rn(r[8*i+3], e0.w);
        float p4 = __fmul_rn(r[8*i+4], e1.x);
        float p5 = __fmul_rn(r[8*i+5], e1.y);
        float p6 = __fmul_rn(r[8*i+6], e1.z);
        float p7 = __fmul_rn(r[8*i+7], e1.w);
        if (i == 0) {
            s[0]=p0; s[1]=p1; s[2]=p2; s[3]=p3;
            s[4]=p4; s[5]=p5; s[6]=p6; s[7]=p7;
        } else {
            s[0]=__fadd_rn(s[0],p0); s[1]=__fadd_rn(s[1],p1);
            s[2]=__fadd_rn(s[2],p2); s[3]=__fadd_rn(s[3],p3);
            s[4]=__fadd_rn(s[4],p4); s[5]=__fadd_rn(s[5],p5);
            s[6]=__fadd_rn(s[6],p6); s[7]=__fadd_rn(s[7],p7);
        }
    }
    float dot = __fadd_rn(
        __fadd_rn(__fadd_rn(s[0], s[1]), __fadd_rn(s[2], s[3])),
        __fadd_rn(__fadd_rn(s[4], s[5]), __fadd_rn(s[6], s[7])));
    return __fsub_rn(t1, __fadd_rn(dot, dot));
}

__global__ __launch_bounds__(128, 3) void rvq_main_kernel(
        const float* __restrict__ x,
        const float* __restrict__ emb,
        float* __restrict__ out,
        unsigned int* __restrict__ cnt,
        double* __restrict__ lossws,
        const float* __restrict__ ee2ws)
{
    const int tid  = threadIdx.x;
    const int gid  = blockIdx.x * 128 + tid;
    const int m    = gid >> 1;            // token
    const int h    = gid & 1;             // code parity owned by this thread
    const int b    = m >> 13;
    const int t    = m & (TT - 1);
    const size_t xb = (size_t)b * (CODE_DIM * (size_t)TT) + (size_t)t;

    float r[CODE_DIM];                    // FULL residual per thread
    #pragma unroll
    for (int n = 0; n < CODE_DIM; ++n)
        r[n] = x[xb + (size_t)n * TT];

    float* __restrict__ outq = out + QOFF;
    float* __restrict__ outi = out + IOFF;

    int hist[N_LAYERS];

    for (int l = 0; l < N_LAYERS; ++l) {
        const float* __restrict__ el  = emb + (size_t)l * NUM_CODE * CODE_DIM;
        const float* __restrict__ e2l = ee2ws + l * NUM_CODE;

        // ---- rr2: exact pairwise-8 (local, full dims) ----
        float rr2;
        {
            float s[8];
            #pragma unroll
            for (int j = 0; j < 8; ++j) s[j] = __fmul_rn(r[j], r[j]);
            #pragma unroll
            for (int i = 8; i < CODE_DIM; i += 8) {
                #pragma unroll
                for (int j = 0; j < 8; ++j)
                    s[j] = __fadd_rn(s[j], __fmul_rn(r[i + j], r[i + j]));
            }
            rr2 = __fadd_rn(
                __fadd_rn(__fadd_rn(s[0], s[1]), __fadd_rn(s[2], s[3])),
                __fadd_rn(__fadd_rn(s[4], s[5]), __fadd_rn(s[6], s[7])));
        }

        // ---- fast scan of my 128 codes (c = 2j+h), full-dim fmaf ----
        float m1 = INFINITY, m2 = INFINITY, m3 = INFINITY;
        int i1 = 0, i2 = 0;
        for (int j = 0; j < NUM_CODE / 2; ++j) {
            const int c = 2 * j + h;
            const float4* ep = reinterpret_cast<const float4*>(
                el + (size_t)c * CODE_DIM);
            float a0 = 0.f, a1 = 0.f, a2 = 0.f, a3 = 0.f;
            #pragma unroll
            for (int d4 = 0; d4 < 8; ++d4) {
                float4 e0 = ep[4*d4+0], e1 = ep[4*d4+1];
                float4 e2v = ep[4*d4+2], e3 = ep[4*d4+3];
                a0 = fmaf(r[16*d4+ 0], e0.x, a0); a1 = fmaf(r[16*d4+ 1], e0.y, a1);
                a2 = fmaf(r[16*d4+ 2], e0.z, a2); a3 = fmaf(r[16*d4+ 3], e0.w, a3);
                a0 = fmaf(r[16*d4+ 4], e1.x, a0); a1 = fmaf(r[16*d4+ 5], e1.y, a1);
                a2 = fmaf(r[16*d4+ 6], e1.z, a2); a3 = fmaf(r[16*d4+ 7], e1.w, a3);
                a0 = fmaf(r[16*d4+ 8], e2v.x, a0); a1 = fmaf(r[16*d4+ 9], e2v.y, a1);
                a2 = fmaf(r[16*d4+10], e2v.z, a2); a3 = fmaf(r[16*d4+11], e2v.w, a3);
                a0 = fmaf(r[16*d4+12], e3.x, a0); a1 = fmaf(r[16*d4+13], e3.y, a1);
                a2 = fmaf(r[16*d4+14], e3.z, a2); a3 = fmaf(r[16*d4+15], e3.w, a3);
            }
            float dot = (a0 + a1) + (a2 + a3);
            float di  = __fsub_rn(__fadd_rn(rr2, e2l[c]), __fadd_rn(dot, dot));
            bool b1 = di < m1, b2 = di < m2, b3 = di < m3;
            m3 = b2 ? m2 : (b3 ? di : m3);
            m2 = b1 ? m1 : (b2 ? di : m2);
            i2 = b1 ? i1 : (b2 ? c  : i2);
            m1 = b1 ? di : m1;
            i1 = b1 ? c  : i1;
        }

        // ---- thread-local tiered exact resolution ----
        float vi; int ii;
        if (m3 - m1 < MARGIN) {                 // rare: 3-way near-tie
            float best = INFINITY; int bidx = 0;
            for (int j = 0; j < NUM_CODE / 2; ++j) {
                int c = 2 * j + h;
                float ex = exact_di(el + (size_t)c * CODE_DIM, r,
                                    __fadd_rn(rr2, e2l[c]));
                if (ex < best) { best = ex; bidx = c; }
            }
            vi = best; ii = bidx;
        } else if (m2 - m1 < MARGIN) {          // ~1%: 2-way near-tie
            int lo = min(i1, i2), hi = max(i1, i2);
            float exlo = exact_di(el + (size_t)lo * CODE_DIM, r,
                                  __fadd_rn(rr2, e2l[lo]));
            float exhi = exact_di(el + (size_t)hi * CODE_DIM, r,
                                  __fadd_rn(rr2, e2l[hi]));
            vi = fminf(exlo, exhi); ii = (exhi < exlo) ? hi : lo;
        } else {                                // clean: fast winner is argmin
            vi = m1; ii = i1;
        }

        // ---- pair merge (one shuffle per layer), margin-aware ----
        float vo = __shfl_xor(vi, 1, 64);
        int   io = __shfl_xor(ii, 1, 64);
        int bi;
        if (vo < vi - MARGIN)      bi = io;
        else if (vi < vo - MARGIN) bi = ii;
        else {
            float exs = exact_di(el + (size_t)ii * CODE_DIM, r,
                                 __fadd_rn(rr2, e2l[ii]));
            float exo = exact_di(el + (size_t)io * CODE_DIM, r,
                                 __fadd_rn(rr2, e2l[io]));
            bi = ((exo < exs) || (exo == exs && io < ii)) ? io : ii;
        }

        hist[l] = bi;
        if (h == 0) {
            outi[(size_t)m * N_LAYERS + l] = (float)bi;
            atomicAdd(&cnt[l * NUM_CODE + bi], 1u);
        }

        // ---- residual update: r = fl(r - e[bi]) (full dims) ----
        const float4* q4 = reinterpret_cast<const float4*>(
            el + (size_t)bi * CODE_DIM);
        #pragma unroll
        for (int d = 0; d < CODE_DIM / 4; ++d) {
            float4 qv = q4[d];
            r[4*d+0] = __fsub_rn(r[4*d+0], qv.x);
            r[4*d+1] = __fsub_rn(r[4*d+1], qv.y);
            r[4*d+2] = __fsub_rn(r[4*d+2], qv.z);
            r[4*d+3] = __fsub_rn(r[4*d+3], qv.w);
        }

        // ---- latent loss (h==0 lanes only; f64 wave reduce) ----
        double ls = 0.0;
        if (h == 0) {
            #pragma unroll
            for (int n = 0; n < CODE_DIM; ++n)
                ls = fma((double)r[n], (double)r[n], ls);
        }
        for (int o = 32; o > 0; o >>= 1)
            ls += __shfl_down(ls, o, 64);
        if ((tid & 63) == 0) atomicAdd(&lossws[l], ls);
    }

    // ---------------- Phase B: LDS-transposed coalesced writes ----------------
    // Thread handles dims n = h*64 + [0,64). Stage v[5] per (n,token) into LDS,
    // then the block stores 8 contiguous 1280B segments as pure float4.
    __shared__ float sb[8 * 64 * 5];            // [h*4+i][tok64][5], 10240 B
    const int t0   = (blockIdx.x * 64) & (TT - 1);   // block's first t (same b)
    const int wtok = tid >> 1;                  // token-in-block 0..63
    const float* prow[N_LAYERS];
    #pragma unroll
    for (int l = 0; l < N_LAYERS; ++l)
        prow[l] = emb + ((size_t)l * NUM_CODE + hist[l]) * CODE_DIM + h * HALF_DIM;

    for (int cc = 0; cc < 16; ++cc) {
        float4 q[N_LAYERS];
        #pragma unroll
        for (int l = 0; l < N_LAYERS; ++l)
            q[l] = reinterpret_cast<const float4*>(prow[l])[cc];
        #pragma unroll
        for (int i = 0; i < 4; ++i) {
            int n = h * HALF_DIM + 4 * cc + i;
            float xv = x[xb + (size_t)n * TT];
            float rr = xv;
            float* dst = &sb[((h * 4 + i) * 64 + wtok) * 5];
            #pragma unroll
            for (int l = 0; l < N_LAYERS; ++l) {
                float qi = (i == 0) ? q[l].x : (i == 1) ? q[l].y
                         : (i == 2) ? q[l].z : q[l].w;
                rr = __fsub_rn(rr, qi);
                dst[l] = __fsub_rn(xv, rr);
            }
        }
        __syncthreads();
        #pragma unroll
        for (int s = 0; s < 5; ++s) {
            int k   = s * 128 + tid;            // 0..639 float4s
            int seg = k / 80;                   // 0..7 = (h*4+i)
            int kk  = k - seg * 80;             // float4 within 1280B segment
            int hh  = seg >> 2, ii2 = seg & 3;
            int n   = hh * HALF_DIM + 4 * cc + ii2;
            float4 val = *reinterpret_cast<const float4*>(&sb[seg * 320 + kk * 4]);
            *reinterpret_cast<float4*>(
                outq + ((size_t)((size_t)b * CODE_DIM + n) * TT + t0) * N_LAYERS
                     + (size_t)kk * 4) = val;
        }
        __syncthreads();
    }
}

__global__ __launch_bounds__(256) void rvq_finalize_kernel(
        const unsigned int* __restrict__ cnt,
        const double* __restrict__ lossws,
        float* __restrict__ out)
{
    __shared__ double sd[256];
    const int k = threadIdx.x;
    const double epsf = 1.1920928955078125e-07;  // float32 eps
    for (int l = 0; l < N_LAYERS; ++l) {
        float p = (float)cnt[l * NUM_CODE + k] / 131072.0f;   // exact (/2^17)
        double term = (double)p * log((double)p + epsf);
        sd[k] = term;
        __syncthreads();
        for (int s = 128; s > 0; s >>= 1) {
            if (k < s) sd[k] += sd[k + s];
            __syncthreads();
        }
        if (k == 0) out[PPLOFF + l] = (float)exp(-sd[0]);
        __syncthreads();
    }
    if (k == 0) {
        double tot = 0.0;
        for (int l = 0; l < N_LAYERS; ++l) tot += lossws[l];
        out[LOSSOFF] = (float)(tot / 16777216.0);   // / (B*N*T)
    }
}

extern "C" void kernel_launch(void* const* d_in, const int* in_sizes, int n_in,
                              void* d_out, int out_size, void* d_ws, size_t ws_size,
                              hipStream_t stream)
{
    const float* x   = (const float*)d_in[0];
    const float* emb = (const float*)d_in[1];
    float* out = (float*)d_out;

    unsigned int* cnt = (unsigned int*)d_ws;
    double* lossws    = (double*)((char*)d_ws + 5120);
    float* ee2ws      = (float*)((char*)d_ws + 5160);

    rvq_init_kernel<<<5, 256, 0, stream>>>(emb, cnt, lossws, ee2ws);
    rvq_main_kernel<<<(2 * MTOK) / 128, 128, 0, stream>>>(x, emb, out, cnt, lossws, ee2ws);
    rvq_finalize_kernel<<<1, 256, 0, stream>>>(cnt, lossws, out);
}

// Round 10
// 5788.959 us; speedup vs baseline: 1.0038x; 1.0038x over previous
//
#include <hip/hip_runtime.h>
#include <math.h>

#define NUM_CODE 256
#define CODE_DIM 128
#define N_LAYERS 5
#define TT 8192
#define MTOK 131072
#define MARGIN 4e-5f

#define QOFF   0ull
#define IOFF   83886080ull              // 16*128*8192*5
#define PPLOFF 84541440ull
#define LOSSOFF 84541445ull

// ws: [0,5120) u32 cnt[5][256]; [5120,5160) double loss[5]; [5160,10280) float ee2[5][256]
//
// Numeric model (CONFIRMED r6-PASS): dot_c / ee2_c = numpy pairwise-8 mul/add
// trees; dist = fl(fl(rr2+ee2_c) - fl(2*dot_c)); argmin first-min; residual
// fl32 subtract. r10 = r6 structure (wave-uniform scalar-load scan, 1
// thread/token) + fmaf fast scan with tiered exact fallback (validated r8/r9)
// + launch_bounds(256,2) so r[128] stays in architectural VGPRs.

__global__ __launch_bounds__(256) void rvq_init_kernel(
        const float* __restrict__ emb,
        unsigned int* __restrict__ cnt,
        double* __restrict__ lossws,
        float* __restrict__ ee2)
{
    int g = blockIdx.x * 256 + threadIdx.x;
    if (g < N_LAYERS) lossws[g] = 0.0;
    if (g < N_LAYERS * NUM_CODE) {
        cnt[g] = 0u;
        const float* e = emb + (size_t)g * CODE_DIM;
        float s[8];
        #pragma unroll
        for (int j = 0; j < 8; ++j) s[j] = __fmul_rn(e[j], e[j]);
        #pragma unroll
        for (int i = 8; i < CODE_DIM; i += 8) {
            #pragma unroll
            for (int j = 0; j < 8; ++j)
                s[j] = __fadd_rn(s[j], __fmul_rn(e[i + j], e[i + j]));
        }
        ee2[g] = __fadd_rn(
            __fadd_rn(__fadd_rn(s[0], s[1]), __fadd_rn(s[2], s[3])),
            __fadd_rn(__fadd_rn(s[4], s[5]), __fadd_rn(s[6], s[7])));
    }
}

// Bitwise-exact reference dist for one code (numpy pairwise-8 mul/add tree).
__device__ __forceinline__ float exact_di(
        const float* __restrict__ row, const float r[CODE_DIM], float t1)
{
    float s[8];
    const float4* rv = reinterpret_cast<const float4*>(row);
    #pragma unroll
    for (int i = 0; i < 16; ++i) {
        float4 e0 = rv[2 * i];
        float4 e1 = rv[2 * i + 1];
        float p0 = __fmul_rn(r[8*i+0], e0.x);
        float p1 = __fmul_rn(r[8*i+1], e0.y);
        float p2 = __fmul_rn(r[8*i+2], e0.z);
        float p3 = __fmul_rn(r[8*i+3], e0.w);
        float p4 = __fmul_rn(r[8*i+4], e1.x);
        float p5 = __fmul_rn(r[8*i+5], e1.y);
        float p6 = __fmul_rn(r[8*i+6], e1.z);
        float p7 = __fmul_rn(r[8*i+7], e1.w);
        if (i == 0) {
            s[0]=p0; s[1]=p1; s[2]=p2; s[3]=p3;
            s[4]=p4; s[5]=p5; s[6]=p6; s[7]=p7;
        } else {
            s[0]=__fadd_rn(s[0],p0); s[1]=__fadd_rn(s[1],p1);
            s[2]=__fadd_rn(s[2],p2); s[3]=__fadd_rn(s[3],p3);
            s[4]=__fadd_rn(s[4],p4); s[5]=__fadd_rn(s[5],p5);
            s[6]=__fadd_rn(s[6],p6); s[7]=__fadd_rn(s[7],p7);
        }
    }
    float dot = __fadd_rn(
        __fadd_rn(__fadd_rn(s[0], s[1]), __fadd_rn(s[2], s[3])),
        __fadd_rn(__fadd_rn(s[4], s[5]), __fadd_rn(s[6], s[7])));
    return __fsub_rn(t1, __fadd_rn(dot, dot));
}

__global__ __launch_bounds__(256, 2) void rvq_main_kernel(
        const float* __restrict__ x,
        const float* __restrict__ emb,
        float* __restrict__ out,
        unsigned int* __restrict__ cnt,
        double* __restrict__ lossws,
        const float* __restrict__ ee2ws)
{
    const int m = blockIdx.x * 256 + threadIdx.x;   // token id = b*T + t
    const int b = m >> 13;
    const int t = m & (TT - 1);
    const size_t xb = (size_t)b * (CODE_DIM * (size_t)TT) + (size_t)t;

    float r[CODE_DIM];
    #pragma unroll
    for (int n = 0; n < CODE_DIM; ++n)
        r[n] = x[xb + (size_t)n * TT];

    float* __restrict__ outq = out + QOFF;
    float* __restrict__ outi = out + IOFF;

    int hist[N_LAYERS];

    for (int l = 0; l < N_LAYERS; ++l) {
        const float* __restrict__ el  = emb + (size_t)l * NUM_CODE * CODE_DIM;
        const float* __restrict__ e2l = ee2ws + l * NUM_CODE;

        // ---- rr2: numpy pairwise-8 (r6 verbatim) ----
        float sr[8];
        #pragma unroll
        for (int j = 0; j < 8; ++j) sr[j] = __fmul_rn(r[j], r[j]);
        #pragma unroll
        for (int i = 8; i < CODE_DIM; i += 8) {
            #pragma unroll
            for (int j = 0; j < 8; ++j)
                sr[j] = __fadd_rn(sr[j], __fmul_rn(r[i + j], r[i + j]));
        }
        const float rr2 = __fadd_rn(
            __fadd_rn(__fadd_rn(sr[0], sr[1]), __fadd_rn(sr[2], sr[3])),
            __fadd_rn(__fadd_rn(sr[4], sr[5]), __fadd_rn(sr[6], sr[7])));

        // ---- fast scan: fmaf 4-acc chains, 8 codes/block, wave-uniform ----
        float m1 = INFINITY, m2 = INFINITY, m3 = INFINITY;
        int i1 = 0, i2 = 0;
        for (int c0 = 0; c0 < NUM_CODE; c0 += 8) {
            const float* eb = el + (size_t)c0 * CODE_DIM;
            float A[8][4];
            #pragma unroll
            for (int j = 0; j < 8; ++j)
                A[j][0] = A[j][1] = A[j][2] = A[j][3] = 0.f;
            #pragma unroll
            for (int d4 = 0; d4 < CODE_DIM / 4; ++d4) {
                #pragma unroll
                for (int j = 0; j < 8; ++j) {
                    float4 e = reinterpret_cast<const float4*>(eb + j * CODE_DIM)[d4];
                    A[j][0] = fmaf(r[4*d4+0], e.x, A[j][0]);
                    A[j][1] = fmaf(r[4*d4+1], e.y, A[j][1]);
                    A[j][2] = fmaf(r[4*d4+2], e.z, A[j][2]);
                    A[j][3] = fmaf(r[4*d4+3], e.w, A[j][3]);
                }
            }
            #pragma unroll
            for (int j = 0; j < 8; ++j) {
                float dot = (A[j][0] + A[j][1]) + (A[j][2] + A[j][3]);
                float di  = __fsub_rn(__fadd_rn(rr2, e2l[c0 + j]),
                                      __fadd_rn(dot, dot));
                bool b1 = di < m1, b2 = di < m2, b3 = di < m3;
                m3 = b2 ? m2 : (b3 ? di : m3);
                m2 = b1 ? m1 : (b2 ? di : m2);
                i2 = b1 ? i1 : (b2 ? (c0 + j) : i2);
                m1 = b1 ? di : m1;
                i1 = b1 ? (c0 + j) : i1;
            }
        }

        // ---- tiered exact resolution (rare; divergence amortized) ----
        int bi = i1;
        if (m3 - m1 < MARGIN) {
            // >=3-way near-tie (~1e-6): full exact rescan, first-min
            float best = INFINITY; int bidx = 0;
            for (int c = 0; c < NUM_CODE; ++c) {
                float ex = exact_di(el + (size_t)c * CODE_DIM, r,
                                    __fadd_rn(rr2, e2l[c]));
                if (ex < best) { best = ex; bidx = c; }
            }
            bi = bidx;
        } else if (m2 - m1 < MARGIN) {
            // 2-way near-tie (~2%): exact duel, first-index on tie
            int lo = min(i1, i2), hi = max(i1, i2);
            float exlo = exact_di(el + (size_t)lo * CODE_DIM, r,
                                  __fadd_rn(rr2, e2l[lo]));
            float exhi = exact_di(el + (size_t)hi * CODE_DIM, r,
                                  __fadd_rn(rr2, e2l[hi]));
            bi = (exhi < exlo) ? hi : lo;
        }

        hist[l] = bi;
        outi[(size_t)m * N_LAYERS + l] = (float)bi;
        atomicAdd(&cnt[l * NUM_CODE + bi], 1u);

        // ---- residual update: r = fl(r - e[bi]) ----
        const float4* q4 = reinterpret_cast<const float4*>(
            el + (size_t)bi * CODE_DIM);
        #pragma unroll
        for (int d = 0; d < CODE_DIM / 4; ++d) {
            float4 qv = q4[d];
            r[4*d+0] = __fsub_rn(r[4*d+0], qv.x);
            r[4*d+1] = __fsub_rn(r[4*d+1], qv.y);
            r[4*d+2] = __fsub_rn(r[4*d+2], qv.z);
            r[4*d+3] = __fsub_rn(r[4*d+3], qv.w);
        }

        // ---- latent loss term: sum r^2 (f64 wave reduce) ----
        double ls = 0.0;
        #pragma unroll
        for (int n = 0; n < CODE_DIM; ++n)
            ls = fma((double)r[n], (double)r[n], ls);
        for (int o = 32; o > 0; o >>= 1)
            ls += __shfl_down(ls, o, 64);
        if ((threadIdx.x & 63) == 0)
            atomicAdd(&lossws[l], ls);
    }

    // ---------------- Phase B: quantized output (r6 verbatim) ----------------
    __shared__ float se[N_LAYERS][NUM_CODE][9];   // +1 pad
    const int NCH = 8;
    for (int chunk = 0; chunk < CODE_DIM / NCH; ++chunk) {
        const int n0 = chunk * NCH;
        __syncthreads();
        #pragma unroll
        for (int i = 0; i < (N_LAYERS * NUM_CODE * NCH) / 256; ++i) {   // 40
            int flat = i * 256 + threadIdx.x;
            int n = flat & (NCH - 1);
            int k = (flat >> 3) & (NUM_CODE - 1);
            int l = flat >> 11;
            se[l][k][n] = emb[((size_t)l * NUM_CODE + k) * CODE_DIM + n0 + n];
        }
        __syncthreads();
        #pragma unroll
        for (int n = 0; n < NCH; ++n) {
            float xv = x[xb + (size_t)(n0 + n) * TT];
            float rr = xv;
            float v[N_LAYERS];
            #pragma unroll
            for (int l = 0; l < N_LAYERS; ++l) {
                rr = __fsub_rn(rr, se[l][hist[l]][n]);
                v[l] = __fsub_rn(xv, rr);
            }
            size_t base = (xb + (size_t)(n0 + n) * TT) * N_LAYERS;
            outq[base + 0] = v[0];
            outq[base + 1] = v[1];
            outq[base + 2] = v[2];
            outq[base + 3] = v[3];
            outq[base + 4] = v[4];
        }
    }
}

__global__ __launch_bounds__(256) void rvq_finalize_kernel(
        const unsigned int* __restrict__ cnt,
        const double* __restrict__ lossws,
        float* __restrict__ out)
{
    __shared__ double sd[256];
    const int k = threadIdx.x;
    const double epsf = 1.1920928955078125e-07;  // float32 eps
    for (int l = 0; l < N_LAYERS; ++l) {
        float p = (float)cnt[l * NUM_CODE + k] / 131072.0f;   // exact (/2^17)
        double term = (double)p * log((double)p + epsf);
        sd[k] = term;
        __syncthreads();
        for (int s = 128; s > 0; s >>= 1) {
            if (k < s) sd[k] += sd[k + s];
            __syncthreads();
        }
        if (k == 0) out[PPLOFF + l] = (float)exp(-sd[0]);
        __syncthreads();
    }
    if (k == 0) {
        double tot = 0.0;
        for (int l = 0; l < N_LAYERS; ++l) tot += lossws[l];
        out[LOSSOFF] = (float)(tot / 16777216.0);   // / (B*N*T)
    }
}

extern "C" void kernel_launch(void* const* d_in, const int* in_sizes, int n_in,
                              void* d_out, int out_size, void* d_ws, size_t ws_size,
                              hipStream_t stream)
{
    const float* x   = (const float*)d_in[0];
    const float* emb = (const float*)d_in[1];
    float* out = (float*)d_out;

    unsigned int* cnt = (unsigned int*)d_ws;
    double* lossws    = (double*)((char*)d_ws + 5120);
    float* ee2ws      = (float*)((char*)d_ws + 5160);

    rvq_init_kernel<<<5, 256, 0, stream>>>(emb, cnt, lossws, ee2ws);
    rvq_main_kernel<<<MTOK / 256, 256, 0, stream>>>(x, emb, out, cnt, lossws, ee2ws);
    rvq_finalize_kernel<<<1, 256, 0, stream>>>(cnt, lossws, out);
}

// Round 11
// 1941.499 us; speedup vs baseline: 2.9929x; 2.9817x over previous
//
#include <hip/hip_runtime.h>
#include <math.h>

#define NUM_CODE 256
#define CODE_DIM 128
#define N_LAYERS 5
#define TT 8192
#define MTOK 131072
#define TOKPB 64
#define MARGIN 1e-4f

#define QOFF   0ull
#define IOFF   83886080ull              // 16*128*8192*5
#define PPLOFF 84541440ull
#define LOSSOFF 84541445ull

// ws: [0,5120) u32 cnt[5][256]; [5120,5160) double loss[5]; [5160,10280) float ee2[5][256]
//
// Numeric model (CONFIRMED r6): dot_c / ee2_c = numpy pairwise-8 mul/add trees;
// dist = fl(fl(rr2+ee2_c) - fl(2*dot_c)); argmin first-min; residual fl32 sub.
// r11: block-local GEMM (64 tokens/block, residual in LDS, acc in registers).
// Fast filter in u-space (u = ee2 - 2dot; rr2 token-constant; |dist-gap -
// u-gap| <= ~3.1e-5 from the two fl(~128)-scale roundings). Tokens with
// u-gap < MARGIN=1e-4 get a cooperative full exact rescan (all 256 codes,
// bitwise reference formula), so every committed index is the reference argmin.

__global__ __launch_bounds__(256) void rvq_init_kernel(
        const float* __restrict__ emb,
        unsigned int* __restrict__ cnt,
        double* __restrict__ lossws,
        float* __restrict__ ee2)
{
    int g = blockIdx.x * 256 + threadIdx.x;
    if (g < N_LAYERS) lossws[g] = 0.0;
    if (g < N_LAYERS * NUM_CODE) {
        cnt[g] = 0u;
        const float* e = emb + (size_t)g * CODE_DIM;
        float s[8];
        #pragma unroll
        for (int j = 0; j < 8; ++j) s[j] = __fmul_rn(e[j], e[j]);
        #pragma unroll
        for (int i = 8; i < CODE_DIM; i += 8) {
            #pragma unroll
            for (int j = 0; j < 8; ++j)
                s[j] = __fadd_rn(s[j], __fmul_rn(e[i + j], e[i + j]));
        }
        ee2[g] = __fadd_rn(
            __fadd_rn(__fadd_rn(s[0], s[1]), __fadd_rn(s[2], s[3])),
            __fadd_rn(__fadd_rn(s[4], s[5]), __fadd_rn(s[6], s[7])));
    }
}

// Exact reference dist: rcol = LDS residual column (stride TOKPB), erow global.
__device__ __forceinline__ float exact_rr2_col(const float* __restrict__ rcol)
{
    float s[8];
    #pragma unroll
    for (int i = 0; i < 16; ++i) {
        #pragma unroll
        for (int j = 0; j < 8; ++j) {
            float rv = rcol[(8 * i + j) * TOKPB];
            float p = __fmul_rn(rv, rv);
            s[j] = (i == 0) ? p : __fadd_rn(s[j], p);
        }
    }
    return __fadd_rn(
        __fadd_rn(__fadd_rn(s[0], s[1]), __fadd_rn(s[2], s[3])),
        __fadd_rn(__fadd_rn(s[4], s[5]), __fadd_rn(s[6], s[7])));
}

__device__ __forceinline__ float exact_dist_col(
        const float* __restrict__ erow, const float* __restrict__ rcol,
        float rr2, float ee2c)
{
    float s[8];
    #pragma unroll
    for (int i = 0; i < 16; ++i) {
        const float4* ev = reinterpret_cast<const float4*>(erow + 8 * i);
        float4 e0 = ev[0], e1 = ev[1];
        float p0 = __fmul_rn(rcol[(8*i+0) * TOKPB], e0.x);
        float p1 = __fmul_rn(rcol[(8*i+1) * TOKPB], e0.y);
        float p2 = __fmul_rn(rcol[(8*i+2) * TOKPB], e0.z);
        float p3 = __fmul_rn(rcol[(8*i+3) * TOKPB], e0.w);
        float p4 = __fmul_rn(rcol[(8*i+4) * TOKPB], e1.x);
        float p5 = __fmul_rn(rcol[(8*i+5) * TOKPB], e1.y);
        float p6 = __fmul_rn(rcol[(8*i+6) * TOKPB], e1.z);
        float p7 = __fmul_rn(rcol[(8*i+7) * TOKPB], e1.w);
        if (i == 0) {
            s[0]=p0; s[1]=p1; s[2]=p2; s[3]=p3;
            s[4]=p4; s[5]=p5; s[6]=p6; s[7]=p7;
        } else {
            s[0]=__fadd_rn(s[0],p0); s[1]=__fadd_rn(s[1],p1);
            s[2]=__fadd_rn(s[2],p2); s[3]=__fadd_rn(s[3],p3);
            s[4]=__fadd_rn(s[4],p4); s[5]=__fadd_rn(s[5],p5);
            s[6]=__fadd_rn(s[6],p6); s[7]=__fadd_rn(s[7],p7);
        }
    }
    float dot = __fadd_rn(
        __fadd_rn(__fadd_rn(s[0], s[1]), __fadd_rn(s[2], s[3])),
        __fadd_rn(__fadd_rn(s[4], s[5]), __fadd_rn(s[6], s[7])));
    float t1 = __fadd_rn(rr2, ee2c);
    return __fsub_rn(t1, __fadd_rn(dot, dot));
}

__global__ __launch_bounds__(256) void rvq_main_kernel(
        const float* __restrict__ x,
        const float* __restrict__ emb,
        float* __restrict__ out,
        unsigned int* __restrict__ cnt,
        double* __restrict__ lossws,
        const float* __restrict__ ee2ws)
{
    __shared__ float A[CODE_DIM][TOKPB];        // residual [k][tok]  32 KB
    __shared__ float Bt[16][NUM_CODE];          // emb chunk [k'][c]  16 KB
    __shared__ float e2s[NUM_CODE];             // 1 KB
    __shared__ float red[8][TOKPB][3];          // quad top-2          6 KB
    __shared__ int   bis[TOKPB];
    __shared__ int   bihist[N_LAYERS][TOKPB];
    __shared__ float rtv[4];
    __shared__ int   rti[4];
    __shared__ double lred[4];

    const int tid = threadIdx.x;
    const int m0  = blockIdx.x * TOKPB;
    const int b   = m0 >> 13;
    const int t0  = m0 & (TT - 1);
    const size_t xbase = (size_t)b * (CODE_DIM * (size_t)TT) + t0;

    float* __restrict__ outq = out + QOFF;
    float* __restrict__ outi = out + IOFF;

    // ---- load residual tile A[k][tok] = x ----
    #pragma unroll
    for (int rep = 0; rep < 8; ++rep) {
        int f4 = rep * 256 + tid;               // 2048 float4
        int k = f4 >> 4;
        int tk = (f4 & 15) * 4;
        float4 v = *reinterpret_cast<const float4*>(x + xbase + (size_t)k * TT + tk);
        *reinterpret_cast<float4*>(&A[k][tk]) = v;
    }

    const int tg = tid >> 5;                    // token group (8 tokens)
    const int cg = tid & 31;                    // code group (8 codes)

    for (int l = 0; l < N_LAYERS; ++l) {
        const float* __restrict__ el = emb + (size_t)l * NUM_CODE * CODE_DIM;
        e2s[tid] = ee2ws[l * NUM_CODE + tid];
        __syncthreads();

        float ee2r[8];
        #pragma unroll
        for (int j = 0; j < 8; ++j) ee2r[j] = e2s[cg * 8 + j];

        float acc[8][8];
        #pragma unroll
        for (int i = 0; i < 8; ++i)
            #pragma unroll
            for (int j = 0; j < 8; ++j) acc[i][j] = 0.f;

        // ---- GEMM: dot(token, code) over K=128 in 8 chunks of 16 ----
        for (int kc = 0; kc < CODE_DIM / 16; ++kc) {
            {   // stage Bt[k'][code]: thread = code
                const float4* ep = reinterpret_cast<const float4*>(
                    el + (size_t)tid * CODE_DIM + kc * 16);
                float4 q0 = ep[0], q1 = ep[1], q2 = ep[2], q3 = ep[3];
                Bt[ 0][tid]=q0.x; Bt[ 1][tid]=q0.y; Bt[ 2][tid]=q0.z; Bt[ 3][tid]=q0.w;
                Bt[ 4][tid]=q1.x; Bt[ 5][tid]=q1.y; Bt[ 6][tid]=q1.z; Bt[ 7][tid]=q1.w;
                Bt[ 8][tid]=q2.x; Bt[ 9][tid]=q2.y; Bt[10][tid]=q2.z; Bt[11][tid]=q2.w;
                Bt[12][tid]=q3.x; Bt[13][tid]=q3.y; Bt[14][tid]=q3.z; Bt[15][tid]=q3.w;
            }
            __syncthreads();
            #pragma unroll
            for (int k = 0; k < 16; ++k) {
                float4 a0 = *reinterpret_cast<const float4*>(&A[kc*16 + k][tg*8]);
                float4 a1 = *reinterpret_cast<const float4*>(&A[kc*16 + k][tg*8 + 4]);
                float4 b0 = *reinterpret_cast<const float4*>(&Bt[k][cg*8]);
                float4 b1 = *reinterpret_cast<const float4*>(&Bt[k][cg*8 + 4]);
                float av[8] = {a0.x,a0.y,a0.z,a0.w,a1.x,a1.y,a1.z,a1.w};
                float bv[8] = {b0.x,b0.y,b0.z,b0.w,b1.x,b1.y,b1.z,b1.w};
                #pragma unroll
                for (int i = 0; i < 8; ++i)
                    #pragma unroll
                    for (int j = 0; j < 8; ++j)
                        acc[i][j] = fmaf(av[i], bv[j], acc[i][j]);
            }
            __syncthreads();
        }

        // ---- epilogue: u-space top-2 per token, quad merge, write red ----
        #pragma unroll
        for (int i = 0; i < 8; ++i) {
            float m1v = INFINITY, m2v = INFINITY;
            int i1v = 0;
            #pragma unroll
            for (int j = 0; j < 8; ++j) {
                float dv = acc[i][j];
                float u = __fsub_rn(ee2r[j], __fadd_rn(dv, dv));
                bool b1 = u < m1v, b2 = u < m2v;
                m2v = b1 ? m1v : (b2 ? u : m2v);
                m1v = b1 ? u : m1v;
                i1v = b1 ? (cg * 8 + j) : i1v;
            }
            #pragma unroll
            for (int d = 1; d <= 2; d <<= 1) {
                float o1 = __shfl_xor(m1v, d, 64);
                int   oi = __shfl_xor(i1v, d, 64);
                float o2 = __shfl_xor(m2v, d, 64);
                if (o1 < m1v)      { m2v = fminf(m1v, o2); m1v = o1; i1v = oi; }
                else if (o1 > m1v) { m2v = fminf(m2v, o1); }
                else               { i1v = min(i1v, oi); m2v = m1v; }
            }
            if ((tid & 3) == 0) {
                red[cg >> 2][tg * 8 + i][0] = m1v;
                red[cg >> 2][tg * 8 + i][1] = __int_as_float(i1v);
                red[cg >> 2][tg * 8 + i][2] = m2v;
            }
        }
        __syncthreads();

        // ---- final per-token merge + flag ----
        if (tid < TOKPB) {
            float g1 = red[0][tid][0];
            int   gi = __float_as_int(red[0][tid][1]);
            float g2 = red[0][tid][2];
            #pragma unroll
            for (int q = 1; q < 8; ++q) {
                float a1 = red[q][tid][0];
                int   ai = __float_as_int(red[q][tid][1]);
                float a2 = red[q][tid][2];
                if (a1 < g1)      { g2 = fminf(g1, a2); g1 = a1; gi = ai; }
                else if (a1 > g1) { g2 = fminf(g2, a1); }
                else              { gi = min(gi, ai); g2 = g1; }
            }
            bis[tid] = (g2 - g1 < MARGIN) ? ~gi : gi;   // flagged -> negative
        }
        __syncthreads();

        // ---- exact rescan for flagged tokens (block-uniform branches) ----
        for (int tok = 0; tok < TOKPB; ++tok) {
            if (bis[tok] >= 0) continue;
            const float* rcol = &A[0][tok];
            float rr2 = exact_rr2_col(rcol);
            float di = exact_dist_col(el + (size_t)tid * CODE_DIM, rcol,
                                      rr2, e2s[tid]);
            float bv = di; int bidx = tid;
            #pragma unroll
            for (int o = 32; o > 0; o >>= 1) {
                float ov = __shfl_down(bv, o, 64);
                int   oi = __shfl_down(bidx, o, 64);
                if (ov < bv || (ov == bv && oi < bidx)) { bv = ov; bidx = oi; }
            }
            if ((tid & 63) == 0) { rtv[tid >> 6] = bv; rti[tid >> 6] = bidx; }
            __syncthreads();
            if (tid == 0) {
                float gv = rtv[0]; int gidx = rti[0];
                #pragma unroll
                for (int w = 1; w < 4; ++w) {
                    if (rtv[w] < gv || (rtv[w] == gv && rti[w] < gidx)) {
                        gv = rtv[w]; gidx = rti[w];
                    }
                }
                bis[tok] = gidx;
            }
            __syncthreads();
        }

        // ---- commit + residual update + loss ----
        if (tid < TOKPB) {
            int bi = bis[tid];
            bihist[l][tid] = bi;
            outi[(size_t)(m0 + tid) * N_LAYERS + l] = (float)bi;
            atomicAdd(&cnt[l * NUM_CODE + bi], 1u);
        }
        {
            int utok = tid >> 2, part = tid & 3;
            int bi = bis[utok];
            const float4* qr = reinterpret_cast<const float4*>(
                el + (size_t)bi * CODE_DIM + part * 32);
            double ls = 0.0;
            #pragma unroll
            for (int q8 = 0; q8 < 8; ++q8) {
                float4 e = qr[q8];
                int k = part * 32 + q8 * 4;
                float r0 = __fsub_rn(A[k + 0][utok], e.x);
                float r1 = __fsub_rn(A[k + 1][utok], e.y);
                float r2 = __fsub_rn(A[k + 2][utok], e.z);
                float r3 = __fsub_rn(A[k + 3][utok], e.w);
                A[k + 0][utok] = r0; A[k + 1][utok] = r1;
                A[k + 2][utok] = r2; A[k + 3][utok] = r3;
                ls = fma((double)r0, (double)r0, ls);
                ls = fma((double)r1, (double)r1, ls);
                ls = fma((double)r2, (double)r2, ls);
                ls = fma((double)r3, (double)r3, ls);
            }
            #pragma unroll
            for (int o = 32; o > 0; o >>= 1)
                ls += __shfl_down(ls, o, 64);
            if ((tid & 63) == 0) lred[tid >> 6] = ls;
        }
        __syncthreads();
        if (tid == 0)
            atomicAdd(&lossws[l], lred[0] + lred[1] + lred[2] + lred[3]);
        __syncthreads();
    }

    // ---------------- Phase B: coalesced quantized output ----------------
    // Overlay staging buffers on A (A no longer needed).
    float* sq  = &A[0][0];                      // [5][64][9]  11520 B
    float* sx  = sq + 5 * 64 * 9;               // [8][64]      2048 B
    float* sob = sx + 8 * 64;                   // [8][64][5]  10240 B

    for (int nc = 0; nc < 16; ++nc) {
        const int n0 = nc * 8;
        __syncthreads();                         // guard prior sob reads / A use
        #pragma unroll
        for (int rep = 0; rep < 3; ++rep) {
            int f4 = rep * 256 + tid;            // 640 float4: q slices
            if (f4 < 640) {
                int row = f4 >> 1;               // l*64 + tok
                int half = f4 & 1;
                int l2 = row >> 6, tok = row & 63;
                float4 v = *reinterpret_cast<const float4*>(
                    emb + ((size_t)l2 * NUM_CODE + bihist[l2][tok]) * CODE_DIM
                        + n0 + half * 4);
                float* d = &sq[row * 9 + half * 4];
                d[0] = v.x; d[1] = v.y; d[2] = v.z; d[3] = v.w;
            }
        }
        if (tid < 128) {                         // x slice [8 n][64 tok]
            int np = tid >> 4, tk = (tid & 15) * 4;
            float4 v = *reinterpret_cast<const float4*>(
                x + xbase + (size_t)(n0 + np) * TT + tk);
            *reinterpret_cast<float4*>(&sx[np * 64 + tk]) = v;
        }
        __syncthreads();
        #pragma unroll
        for (int rep = 0; rep < 2; ++rep) {
            int cell = rep * 256 + tid;          // 512 cells
            int np = cell >> 6, tok = cell & 63;
            float xv = sx[np * 64 + tok];
            float rr = xv;
            float* dst = &sob[(np * 64 + tok) * 5];
            #pragma unroll
            for (int l2 = 0; l2 < N_LAYERS; ++l2) {
                rr = __fsub_rn(rr, sq[(l2 * 64 + tok) * 9 + np]);
                dst[l2] = __fsub_rn(xv, rr);
            }
        }
        __syncthreads();
        #pragma unroll
        for (int rep = 0; rep < 3; ++rep) {
            int f4 = rep * 256 + tid;            // 640 float4 out
            if (f4 < 640) {
                int np = f4 / 80, kk = f4 % 80;
                float4 v = *reinterpret_cast<const float4*>(&sob[np * 320 + kk * 4]);
                *reinterpret_cast<float4*>(
                    outq + ((size_t)((size_t)b * CODE_DIM + n0 + np) * TT + t0)
                             * N_LAYERS + kk * 4) = v;
            }
        }
    }
}

__global__ __launch_bounds__(256) void rvq_finalize_kernel(
        const unsigned int* __restrict__ cnt,
        const double* __restrict__ lossws,
        float* __restrict__ out)
{
    __shared__ double sd[256];
    const int k = threadIdx.x;
    const double epsf = 1.1920928955078125e-07;  // float32 eps
    for (int l = 0; l < N_LAYERS; ++l) {
        float p = (float)cnt[l * NUM_CODE + k] / 131072.0f;   // exact (/2^17)
        double term = (double)p * log((double)p + epsf);
        sd[k] = term;
        __syncthreads();
        for (int s = 128; s > 0; s >>= 1) {
            if (k < s) sd[k] += sd[k + s];
            __syncthreads();
        }
        if (k == 0) out[PPLOFF + l] = (float)exp(-sd[0]);
        __syncthreads();
    }
    if (k == 0) {
        double tot = 0.0;
        for (int l = 0; l < N_LAYERS; ++l) tot += lossws[l];
        out[LOSSOFF] = (float)(tot / 16777216.0);   // / (B*N*T)
    }
}

extern "C" void kernel_launch(void* const* d_in, const int* in_sizes, int n_in,
                              void* d_out, int out_size, void* d_ws, size_t ws_size,
                              hipStream_t stream)
{
    const float* x   = (const float*)d_in[0];
    const float* emb = (const float*)d_in[1];
    float* out = (float*)d_out;

    unsigned int* cnt = (unsigned int*)d_ws;
    double* lossws    = (double*)((char*)d_ws + 5120);
    float* ee2ws      = (float*)((char*)d_ws + 5160);

    rvq_init_kernel<<<5, 256, 0, stream>>>(emb, cnt, lossws, ee2ws);
    rvq_main_kernel<<<MTOK / TOKPB, 256, 0, stream>>>(x, emb, out, cnt, lossws, ee2ws);
    rvq_finalize_kernel<<<1, 256, 0, stream>>>(cnt, lossws, out);
}

// Round 12
// 1450.313 us; speedup vs baseline: 4.0066x; 1.3387x over previous
//
#include <hip/hip_runtime.h>
#include <math.h>

#define NUM_CODE 256
#define CODE_DIM 128
#define N_LAYERS 5
#define TT 8192
#define MTOK 131072
#define TOKPB 64
#define MARGIN 1e-4f

#define QOFF   0ull
#define IOFF   83886080ull              // 16*128*8192*5
#define PPLOFF 84541440ull
#define LOSSOFF 84541445ull

// ws: [0,5120) u32 cnt[5][256]; [5120,5160) double loss[5]; [5160,10280) float ee2[5][256]
//
// Numeric model (CONFIRMED r6): dot_c / ee2_c = numpy pairwise-8 mul/add trees;
// dist = fl(fl(rr2+ee2_c) - fl(2*dot_c)); argmin first-min; residual fl32 sub.
// r12 = r11 block-GEMM with conflict-free LDS access patterns:
//   - thread's codes = {cg*4..cg*4+3, 128+cg*4..+3} -> B-reads lane-stride 16B
//   - residual update: utok=tid&63, part=tid>>6 -> 2-way (free)
//   - top-2 merge in-register via shfl_xor width 32 (code axis == half-wave)
// Fast filter in u-space (u = ee2-2dot); tokens with u-gap < MARGIN get the
// cooperative bitwise-exact rescan (r11-validated).

__global__ __launch_bounds__(256) void rvq_init_kernel(
        const float* __restrict__ emb,
        unsigned int* __restrict__ cnt,
        double* __restrict__ lossws,
        float* __restrict__ ee2)
{
    int g = blockIdx.x * 256 + threadIdx.x;
    if (g < N_LAYERS) lossws[g] = 0.0;
    if (g < N_LAYERS * NUM_CODE) {
        cnt[g] = 0u;
        const float* e = emb + (size_t)g * CODE_DIM;
        float s[8];
        #pragma unroll
        for (int j = 0; j < 8; ++j) s[j] = __fmul_rn(e[j], e[j]);
        #pragma unroll
        for (int i = 8; i < CODE_DIM; i += 8) {
            #pragma unroll
            for (int j = 0; j < 8; ++j)
                s[j] = __fadd_rn(s[j], __fmul_rn(e[i + j], e[i + j]));
        }
        ee2[g] = __fadd_rn(
            __fadd_rn(__fadd_rn(s[0], s[1]), __fadd_rn(s[2], s[3])),
            __fadd_rn(__fadd_rn(s[4], s[5]), __fadd_rn(s[6], s[7])));
    }
}

// Exact reference dist helpers (r11-validated). rcol = LDS residual column.
__device__ __forceinline__ float exact_rr2_col(const float* __restrict__ rcol)
{
    float s[8];
    #pragma unroll
    for (int i = 0; i < 16; ++i) {
        #pragma unroll
        for (int j = 0; j < 8; ++j) {
            float rv = rcol[(8 * i + j) * TOKPB];
            float p = __fmul_rn(rv, rv);
            s[j] = (i == 0) ? p : __fadd_rn(s[j], p);
        }
    }
    return __fadd_rn(
        __fadd_rn(__fadd_rn(s[0], s[1]), __fadd_rn(s[2], s[3])),
        __fadd_rn(__fadd_rn(s[4], s[5]), __fadd_rn(s[6], s[7])));
}

__device__ __forceinline__ float exact_dist_col(
        const float* __restrict__ erow, const float* __restrict__ rcol,
        float rr2, float ee2c)
{
    float s[8];
    #pragma unroll
    for (int i = 0; i < 16; ++i) {
        const float4* ev = reinterpret_cast<const float4*>(erow + 8 * i);
        float4 e0 = ev[0], e1 = ev[1];
        float p0 = __fmul_rn(rcol[(8*i+0) * TOKPB], e0.x);
        float p1 = __fmul_rn(rcol[(8*i+1) * TOKPB], e0.y);
        float p2 = __fmul_rn(rcol[(8*i+2) * TOKPB], e0.z);
        float p3 = __fmul_rn(rcol[(8*i+3) * TOKPB], e0.w);
        float p4 = __fmul_rn(rcol[(8*i+4) * TOKPB], e1.x);
        float p5 = __fmul_rn(rcol[(8*i+5) * TOKPB], e1.y);
        float p6 = __fmul_rn(rcol[(8*i+6) * TOKPB], e1.z);
        float p7 = __fmul_rn(rcol[(8*i+7) * TOKPB], e1.w);
        if (i == 0) {
            s[0]=p0; s[1]=p1; s[2]=p2; s[3]=p3;
            s[4]=p4; s[5]=p5; s[6]=p6; s[7]=p7;
        } else {
            s[0]=__fadd_rn(s[0],p0); s[1]=__fadd_rn(s[1],p1);
            s[2]=__fadd_rn(s[2],p2); s[3]=__fadd_rn(s[3],p3);
            s[4]=__fadd_rn(s[4],p4); s[5]=__fadd_rn(s[5],p5);
            s[6]=__fadd_rn(s[6],p6); s[7]=__fadd_rn(s[7],p7);
        }
    }
    float dot = __fadd_rn(
        __fadd_rn(__fadd_rn(s[0], s[1]), __fadd_rn(s[2], s[3])),
        __fadd_rn(__fadd_rn(s[4], s[5]), __fadd_rn(s[6], s[7])));
    float t1 = __fadd_rn(rr2, ee2c);
    return __fsub_rn(t1, __fadd_rn(dot, dot));
}

__global__ __launch_bounds__(256, 3) void rvq_main_kernel(
        const float* __restrict__ x,
        const float* __restrict__ emb,
        float* __restrict__ out,
        unsigned int* __restrict__ cnt,
        double* __restrict__ lossws,
        const float* __restrict__ ee2ws)
{
    __shared__ float A[CODE_DIM][TOKPB];        // residual [k][tok]  32 KB
    __shared__ float Bt[16][NUM_CODE];          // emb chunk [k'][c]  16 KB
    __shared__ float e2s[NUM_CODE];             // 1 KB
    __shared__ int   bis[TOKPB];
    __shared__ int   bihist[N_LAYERS][TOKPB];
    __shared__ float rtv[4];
    __shared__ int   rti[4];
    __shared__ double lred[4];

    const int tid = threadIdx.x;
    const int m0  = blockIdx.x * TOKPB;
    const int b   = m0 >> 13;
    const int t0  = m0 & (TT - 1);
    const size_t xbase = (size_t)b * (CODE_DIM * (size_t)TT) + t0;

    float* __restrict__ outq = out + QOFF;
    float* __restrict__ outi = out + IOFF;

    // ---- load residual tile A[k][tok] = x (conflict-free) ----
    #pragma unroll
    for (int rep = 0; rep < 8; ++rep) {
        int f4 = rep * 256 + tid;               // 2048 float4
        int k = f4 >> 4;
        int tk = (f4 & 15) * 4;
        float4 v = *reinterpret_cast<const float4*>(x + xbase + (size_t)k * TT + tk);
        *reinterpret_cast<float4*>(&A[k][tk]) = v;
    }

    const int tg = tid >> 5;                    // token octet 0..7
    const int cg = tid & 31;                    // code slot 0..31
    // thread's codes: j<4 -> cg*4+j ; j>=4 -> 128+cg*4+(j-4)

    for (int l = 0; l < N_LAYERS; ++l) {
        const float* __restrict__ el = emb + (size_t)l * NUM_CODE * CODE_DIM;
        e2s[tid] = ee2ws[l * NUM_CODE + tid];
        __syncthreads();

        float ee2r[8];
        #pragma unroll
        for (int j = 0; j < 4; ++j) {
            ee2r[j]     = e2s[cg * 4 + j];
            ee2r[4 + j] = e2s[128 + cg * 4 + j];
        }

        float acc[8][8];
        #pragma unroll
        for (int i = 0; i < 8; ++i)
            #pragma unroll
            for (int j = 0; j < 8; ++j) acc[i][j] = 0.f;

        // ---- GEMM: dot(token, code) over K=128 in 8 chunks of 16 ----
        for (int kc = 0; kc < CODE_DIM / 16; ++kc) {
            {   // stage Bt[k'][code]: thread = code (lane-consecutive writes)
                const float4* ep = reinterpret_cast<const float4*>(
                    el + (size_t)tid * CODE_DIM + kc * 16);
                float4 q0 = ep[0], q1 = ep[1], q2 = ep[2], q3 = ep[3];
                Bt[ 0][tid]=q0.x; Bt[ 1][tid]=q0.y; Bt[ 2][tid]=q0.z; Bt[ 3][tid]=q0.w;
                Bt[ 4][tid]=q1.x; Bt[ 5][tid]=q1.y; Bt[ 6][tid]=q1.z; Bt[ 7][tid]=q1.w;
                Bt[ 8][tid]=q2.x; Bt[ 9][tid]=q2.y; Bt[10][tid]=q2.z; Bt[11][tid]=q2.w;
                Bt[12][tid]=q3.x; Bt[13][tid]=q3.y; Bt[14][tid]=q3.z; Bt[15][tid]=q3.w;
            }
            __syncthreads();
            #pragma unroll
            for (int k = 0; k < 16; ++k) {
                float4 a0 = *reinterpret_cast<const float4*>(&A[kc*16 + k][tg*8]);
                float4 a1 = *reinterpret_cast<const float4*>(&A[kc*16 + k][tg*8 + 4]);
                float4 b0 = *reinterpret_cast<const float4*>(&Bt[k][cg*4]);        // stride-16B
                float4 b1 = *reinterpret_cast<const float4*>(&Bt[k][128 + cg*4]);  // stride-16B
                float av[8] = {a0.x,a0.y,a0.z,a0.w,a1.x,a1.y,a1.z,a1.w};
                float bv[8] = {b0.x,b0.y,b0.z,b0.w,b1.x,b1.y,b1.z,b1.w};
                #pragma unroll
                for (int i = 0; i < 8; ++i)
                    #pragma unroll
                    for (int j = 0; j < 8; ++j)
                        acc[i][j] = fmaf(av[i], bv[j], acc[i][j]);
            }
            __syncthreads();
        }

        // ---- epilogue: u-space top-2 per token, in-register merge (w=32) ----
        #pragma unroll
        for (int i = 0; i < 8; ++i) {
            float m1v = INFINITY, m2v = INFINITY;
            int i1v = 0;
            #pragma unroll
            for (int j = 0; j < 8; ++j) {
                float dv = acc[i][j];
                float u = __fsub_rn(ee2r[j], __fadd_rn(dv, dv));
                int cj = (j < 4) ? (cg * 4 + j) : (128 + cg * 4 + j - 4);
                bool b1 = u < m1v, b2 = u < m2v;
                m2v = b1 ? m1v : (b2 ? u : m2v);
                m1v = b1 ? u : m1v;
                i1v = b1 ? cj : i1v;
            }
            #pragma unroll
            for (int d = 1; d < 32; d <<= 1) {
                float o1 = __shfl_xor(m1v, d, 32);
                int   oi = __shfl_xor(i1v, d, 32);
                float o2 = __shfl_xor(m2v, d, 32);
                if (o1 < m1v)      { m2v = fminf(m1v, o2); m1v = o1; i1v = oi; }
                else if (o1 > m1v) { m2v = fminf(m2v, o1); }
                else               { i1v = min(i1v, oi); m2v = m1v; }
            }
            if (cg == 0)
                bis[tg * 8 + i] = (m2v - m1v < MARGIN) ? ~i1v : i1v;
        }
        __syncthreads();

        // ---- exact rescan for flagged tokens (block-uniform) ----
        for (int tok = 0; tok < TOKPB; ++tok) {
            if (bis[tok] >= 0) continue;
            const float* rcol = &A[0][tok];
            float rr2 = exact_rr2_col(rcol);
            float di = exact_dist_col(el + (size_t)tid * CODE_DIM, rcol,
                                      rr2, e2s[tid]);
            float bv = di; int bidx = tid;
            #pragma unroll
            for (int o = 32; o > 0; o >>= 1) {
                float ov = __shfl_down(bv, o, 64);
                int   oi = __shfl_down(bidx, o, 64);
                if (ov < bv || (ov == bv && oi < bidx)) { bv = ov; bidx = oi; }
            }
            if ((tid & 63) == 0) { rtv[tid >> 6] = bv; rti[tid >> 6] = bidx; }
            __syncthreads();
            if (tid == 0) {
                float gv = rtv[0]; int gidx = rti[0];
                #pragma unroll
                for (int w = 1; w < 4; ++w) {
                    if (rtv[w] < gv || (rtv[w] == gv && rti[w] < gidx)) {
                        gv = rtv[w]; gidx = rti[w];
                    }
                }
                bis[tok] = gidx;
            }
            __syncthreads();
        }

        // ---- commit ----
        if (tid < TOKPB) {
            int bi = bis[tid];
            bihist[l][tid] = bi;
            outi[(size_t)(m0 + tid) * N_LAYERS + l] = (float)bi;
            atomicAdd(&cnt[l * NUM_CODE + bi], 1u);
        }

        // ---- residual update + loss: utok=tid&63 (2-way free), part=tid>>6 ----
        {
            int utok = tid & 63, part = tid >> 6;
            int bi = bis[utok];
            const float4* qr = reinterpret_cast<const float4*>(
                el + (size_t)bi * CODE_DIM + part * 32);
            double ls = 0.0;
            #pragma unroll
            for (int q8 = 0; q8 < 8; ++q8) {
                float4 e = qr[q8];
                int k = part * 32 + q8 * 4;
                float r0 = __fsub_rn(A[k + 0][utok], e.x);
                float r1 = __fsub_rn(A[k + 1][utok], e.y);
                float r2 = __fsub_rn(A[k + 2][utok], e.z);
                float r3 = __fsub_rn(A[k + 3][utok], e.w);
                A[k + 0][utok] = r0; A[k + 1][utok] = r1;
                A[k + 2][utok] = r2; A[k + 3][utok] = r3;
                ls = fma((double)r0, (double)r0, ls);
                ls = fma((double)r1, (double)r1, ls);
                ls = fma((double)r2, (double)r2, ls);
                ls = fma((double)r3, (double)r3, ls);
            }
            #pragma unroll
            for (int o = 32; o > 0; o >>= 1)
                ls += __shfl_down(ls, o, 64);
            if ((tid & 63) == 0) lred[tid >> 6] = ls;
        }
        __syncthreads();
        if (tid == 0)
            atomicAdd(&lossws[l], lred[0] + lred[1] + lred[2] + lred[3]);
        __syncthreads();
    }

    // ---------------- Phase B: coalesced quantized output (r11-validated) ----
    float* sq  = &A[0][0];                      // [5][64][9]  11520 B
    float* sx  = sq + 5 * 64 * 9;               // [8][64]      2048 B
    float* sob = sx + 8 * 64;                   // [8][64][5]  10240 B

    for (int nc = 0; nc < 16; ++nc) {
        const int n0 = nc * 8;
        __syncthreads();
        #pragma unroll
        for (int rep = 0; rep < 3; ++rep) {
            int f4 = rep * 256 + tid;            // 640 float4: q slices
            if (f4 < 640) {
                int row = f4 >> 1;               // l*64 + tok
                int half = f4 & 1;
                int l2 = row >> 6, tok = row & 63;
                float4 v = *reinterpret_cast<const float4*>(
                    emb + ((size_t)l2 * NUM_CODE + bihist[l2][tok]) * CODE_DIM
                        + n0 + half * 4);
                float* d = &sq[row * 9 + half * 4];
                d[0] = v.x; d[1] = v.y; d[2] = v.z; d[3] = v.w;
            }
        }
        if (tid < 128) {                         // x slice [8 n][64 tok]
            int np = tid >> 4, tk = (tid & 15) * 4;
            float4 v = *reinterpret_cast<const float4*>(
                x + xbase + (size_t)(n0 + np) * TT + tk);
            *reinterpret_cast<float4*>(&sx[np * 64 + tk]) = v;
        }
        __syncthreads();
        #pragma unroll
        for (int rep = 0; rep < 2; ++rep) {
            int cell = rep * 256 + tid;          // 512 cells
            int np = cell >> 6, tok = cell & 63;
            float xv = sx[np * 64 + tok];
            float rr = xv;
            float* dst = &sob[(np * 64 + tok) * 5];
            #pragma unroll
            for (int l2 = 0; l2 < N_LAYERS; ++l2) {
                rr = __fsub_rn(rr, sq[(l2 * 64 + tok) * 9 + np]);
                dst[l2] = __fsub_rn(xv, rr);
            }
        }
        __syncthreads();
        #pragma unroll
        for (int rep = 0; rep < 3; ++rep) {
            int f4 = rep * 256 + tid;            // 640 float4 out
            if (f4 < 640) {
                int np = f4 / 80, kk = f4 % 80;
                float4 v = *reinterpret_cast<const float4*>(&sob[np * 320 + kk * 4]);
                *reinterpret_cast<float4*>(
                    outq + ((size_t)((size_t)b * CODE_DIM + n0 + np) * TT + t0)
                             * N_LAYERS + kk * 4) = v;
            }
        }
    }
}

__global__ __launch_bounds__(256) void rvq_finalize_kernel(
        const unsigned int* __restrict__ cnt,
        const double* __restrict__ lossws,
        float* __restrict__ out)
{
    __shared__ double sd[256];
    const int k = threadIdx.x;
    const double epsf = 1.1920928955078125e-07;  // float32 eps
    for (int l = 0; l < N_LAYERS; ++l) {
        float p = (float)cnt[l * NUM_CODE + k] / 131072.0f;   // exact (/2^17)
        double term = (double)p * log((double)p + epsf);
        sd[k] = term;
        __syncthreads();
        for (int s = 128; s > 0; s >>= 1) {
            if (k < s) sd[k] += sd[k + s];
            __syncthreads();
        }
        if (k == 0) out[PPLOFF + l] = (float)exp(-sd[0]);
        __syncthreads();
    }
    if (k == 0) {
        double tot = 0.0;
        for (int l = 0; l < N_LAYERS; ++l) tot += lossws[l];
        out[LOSSOFF] = (float)(tot / 16777216.0);   // / (B*N*T)
    }
}

extern "C" void kernel_launch(void* const* d_in, const int* in_sizes, int n_in,
                              void* d_out, int out_size, void* d_ws, size_t ws_size,
                              hipStream_t stream)
{
    const float* x   = (const float*)d_in[0];
    const float* emb = (const float*)d_in[1];
    float* out = (float*)d_out;

    unsigned int* cnt = (unsigned int*)d_ws;
    double* lossws    = (double*)((char*)d_ws + 5120);
    float* ee2ws      = (float*)((char*)d_ws + 5160);

    rvq_init_kernel<<<5, 256, 0, stream>>>(emb, cnt, lossws, ee2ws);
    rvq_main_kernel<<<MTOK / TOKPB, 256, 0, stream>>>(x, emb, out, cnt, lossws, ee2ws);
    rvq_finalize_kernel<<<1, 256, 0, stream>>>(cnt, lossws, out);
}

// Round 13
// 1435.552 us; speedup vs baseline: 4.0478x; 1.0103x over previous
//
#include <hip/hip_runtime.h>
#include <math.h>

#define NUM_CODE 256
#define CODE_DIM 128
#define N_LAYERS 5
#define TT 8192
#define MTOK 131072
#define TOKPB 64
#define MARGIN 1e-4f

#define QOFF   0ull
#define IOFF   83886080ull              // 16*128*8192*5
#define PPLOFF 84541440ull
#define LOSSOFF 84541445ull

// ws: [0,5120) u32 cnt[5][256]; [5120,5160) double loss[5]; [5160,10280) float ee2[5][256]
//
// Numeric model (CONFIRMED r6): dot_c / ee2_c = numpy pairwise-8 mul/add trees;
// dist = fl(fl(rr2+ee2_c) - fl(2*dot_c)); argmin first-min; residual fl32 sub.
// r13 = r12 with plain __launch_bounds__(256): r12's (256,3) capped VGPR at 84,
// spilling acc[8][8] to scratch (VGPR 176->84, WRITE 344MB->2.3GB = the spill
// traffic). Plain bounds restore r11's no-spill allocation (176 VGPR).

__global__ __launch_bounds__(256) void rvq_init_kernel(
        const float* __restrict__ emb,
        unsigned int* __restrict__ cnt,
        double* __restrict__ lossws,
        float* __restrict__ ee2)
{
    int g = blockIdx.x * 256 + threadIdx.x;
    if (g < N_LAYERS) lossws[g] = 0.0;
    if (g < N_LAYERS * NUM_CODE) {
        cnt[g] = 0u;
        const float* e = emb + (size_t)g * CODE_DIM;
        float s[8];
        #pragma unroll
        for (int j = 0; j < 8; ++j) s[j] = __fmul_rn(e[j], e[j]);
        #pragma unroll
        for (int i = 8; i < CODE_DIM; i += 8) {
            #pragma unroll
            for (int j = 0; j < 8; ++j)
                s[j] = __fadd_rn(s[j], __fmul_rn(e[i + j], e[i + j]));
        }
        ee2[g] = __fadd_rn(
            __fadd_rn(__fadd_rn(s[0], s[1]), __fadd_rn(s[2], s[3])),
            __fadd_rn(__fadd_rn(s[4], s[5]), __fadd_rn(s[6], s[7])));
    }
}

// Exact reference dist helpers (r11/r12-validated). rcol = LDS residual column.
__device__ __forceinline__ float exact_rr2_col(const float* __restrict__ rcol)
{
    float s[8];
    #pragma unroll
    for (int i = 0; i < 16; ++i) {
        #pragma unroll
        for (int j = 0; j < 8; ++j) {
            float rv = rcol[(8 * i + j) * TOKPB];
            float p = __fmul_rn(rv, rv);
            s[j] = (i == 0) ? p : __fadd_rn(s[j], p);
        }
    }
    return __fadd_rn(
        __fadd_rn(__fadd_rn(s[0], s[1]), __fadd_rn(s[2], s[3])),
        __fadd_rn(__fadd_rn(s[4], s[5]), __fadd_rn(s[6], s[7])));
}

__device__ __forceinline__ float exact_dist_col(
        const float* __restrict__ erow, const float* __restrict__ rcol,
        float rr2, float ee2c)
{
    float s[8];
    #pragma unroll
    for (int i = 0; i < 16; ++i) {
        const float4* ev = reinterpret_cast<const float4*>(erow + 8 * i);
        float4 e0 = ev[0], e1 = ev[1];
        float p0 = __fmul_rn(rcol[(8*i+0) * TOKPB], e0.x);
        float p1 = __fmul_rn(rcol[(8*i+1) * TOKPB], e0.y);
        float p2 = __fmul_rn(rcol[(8*i+2) * TOKPB], e0.z);
        float p3 = __fmul_rn(rcol[(8*i+3) * TOKPB], e0.w);
        float p4 = __fmul_rn(rcol[(8*i+4) * TOKPB], e1.x);
        float p5 = __fmul_rn(rcol[(8*i+5) * TOKPB], e1.y);
        float p6 = __fmul_rn(rcol[(8*i+6) * TOKPB], e1.z);
        float p7 = __fmul_rn(rcol[(8*i+7) * TOKPB], e1.w);
        if (i == 0) {
            s[0]=p0; s[1]=p1; s[2]=p2; s[3]=p3;
            s[4]=p4; s[5]=p5; s[6]=p6; s[7]=p7;
        } else {
            s[0]=__fadd_rn(s[0],p0); s[1]=__fadd_rn(s[1],p1);
            s[2]=__fadd_rn(s[2],p2); s[3]=__fadd_rn(s[3],p3);
            s[4]=__fadd_rn(s[4],p4); s[5]=__fadd_rn(s[5],p5);
            s[6]=__fadd_rn(s[6],p6); s[7]=__fadd_rn(s[7],p7);
        }
    }
    float dot = __fadd_rn(
        __fadd_rn(__fadd_rn(s[0], s[1]), __fadd_rn(s[2], s[3])),
        __fadd_rn(__fadd_rn(s[4], s[5]), __fadd_rn(s[6], s[7])));
    float t1 = __fadd_rn(rr2, ee2c);
    return __fsub_rn(t1, __fadd_rn(dot, dot));
}

__global__ __launch_bounds__(256) void rvq_main_kernel(
        const float* __restrict__ x,
        const float* __restrict__ emb,
        float* __restrict__ out,
        unsigned int* __restrict__ cnt,
        double* __restrict__ lossws,
        const float* __restrict__ ee2ws)
{
    __shared__ float A[CODE_DIM][TOKPB];        // residual [k][tok]  32 KB
    __shared__ float Bt[16][NUM_CODE];          // emb chunk [k'][c]  16 KB
    __shared__ float e2s[NUM_CODE];             // 1 KB
    __shared__ int   bis[TOKPB];
    __shared__ int   bihist[N_LAYERS][TOKPB];
    __shared__ float rtv[4];
    __shared__ int   rti[4];
    __shared__ double lred[4];

    const int tid = threadIdx.x;
    const int m0  = blockIdx.x * TOKPB;
    const int b   = m0 >> 13;
    const int t0  = m0 & (TT - 1);
    const size_t xbase = (size_t)b * (CODE_DIM * (size_t)TT) + t0;

    float* __restrict__ outq = out + QOFF;
    float* __restrict__ outi = out + IOFF;

    // ---- load residual tile A[k][tok] = x (conflict-free) ----
    #pragma unroll
    for (int rep = 0; rep < 8; ++rep) {
        int f4 = rep * 256 + tid;               // 2048 float4
        int k = f4 >> 4;
        int tk = (f4 & 15) * 4;
        float4 v = *reinterpret_cast<const float4*>(x + xbase + (size_t)k * TT + tk);
        *reinterpret_cast<float4*>(&A[k][tk]) = v;
    }

    const int tg = tid >> 5;                    // token octet 0..7
    const int cg = tid & 31;                    // code slot 0..31
    // thread's codes: j<4 -> cg*4+j ; j>=4 -> 128+cg*4+(j-4)

    for (int l = 0; l < N_LAYERS; ++l) {
        const float* __restrict__ el = emb + (size_t)l * NUM_CODE * CODE_DIM;
        e2s[tid] = ee2ws[l * NUM_CODE + tid];
        __syncthreads();

        float ee2r[8];
        #pragma unroll
        for (int j = 0; j < 4; ++j) {
            ee2r[j]     = e2s[cg * 4 + j];
            ee2r[4 + j] = e2s[128 + cg * 4 + j];
        }

        float acc[8][8];
        #pragma unroll
        for (int i = 0; i < 8; ++i)
            #pragma unroll
            for (int j = 0; j < 8; ++j) acc[i][j] = 0.f;

        // ---- GEMM: dot(token, code) over K=128 in 8 chunks of 16 ----
        for (int kc = 0; kc < CODE_DIM / 16; ++kc) {
            {   // stage Bt[k'][code]: thread = code (lane-consecutive writes)
                const float4* ep = reinterpret_cast<const float4*>(
                    el + (size_t)tid * CODE_DIM + kc * 16);
                float4 q0 = ep[0], q1 = ep[1], q2 = ep[2], q3 = ep[3];
                Bt[ 0][tid]=q0.x; Bt[ 1][tid]=q0.y; Bt[ 2][tid]=q0.z; Bt[ 3][tid]=q0.w;
                Bt[ 4][tid]=q1.x; Bt[ 5][tid]=q1.y; Bt[ 6][tid]=q1.z; Bt[ 7][tid]=q1.w;
                Bt[ 8][tid]=q2.x; Bt[ 9][tid]=q2.y; Bt[10][tid]=q2.z; Bt[11][tid]=q2.w;
                Bt[12][tid]=q3.x; Bt[13][tid]=q3.y; Bt[14][tid]=q3.z; Bt[15][tid]=q3.w;
            }
            __syncthreads();
            #pragma unroll
            for (int k = 0; k < 16; ++k) {
                float4 a0 = *reinterpret_cast<const float4*>(&A[kc*16 + k][tg*8]);
                float4 a1 = *reinterpret_cast<const float4*>(&A[kc*16 + k][tg*8 + 4]);
                float4 b0 = *reinterpret_cast<const float4*>(&Bt[k][cg*4]);        // stride-16B
                float4 b1 = *reinterpret_cast<const float4*>(&Bt[k][128 + cg*4]);  // stride-16B
                float av[8] = {a0.x,a0.y,a0.z,a0.w,a1.x,a1.y,a1.z,a1.w};
                float bv[8] = {b0.x,b0.y,b0.z,b0.w,b1.x,b1.y,b1.z,b1.w};
                #pragma unroll
                for (int i = 0; i < 8; ++i)
                    #pragma unroll
                    for (int j = 0; j < 8; ++j)
                        acc[i][j] = fmaf(av[i], bv[j], acc[i][j]);
            }
            __syncthreads();
        }

        // ---- epilogue: u-space top-2 per token, in-register merge (w=32) ----
        #pragma unroll
        for (int i = 0; i < 8; ++i) {
            float m1v = INFINITY, m2v = INFINITY;
            int i1v = 0;
            #pragma unroll
            for (int j = 0; j < 8; ++j) {
                float dv = acc[i][j];
                float u = __fsub_rn(ee2r[j], __fadd_rn(dv, dv));
                int cj = (j < 4) ? (cg * 4 + j) : (128 + cg * 4 + j - 4);
                bool b1 = u < m1v, b2 = u < m2v;
                m2v = b1 ? m1v : (b2 ? u : m2v);
                m1v = b1 ? u : m1v;
                i1v = b1 ? cj : i1v;
            }
            #pragma unroll
            for (int d = 1; d < 32; d <<= 1) {
                float o1 = __shfl_xor(m1v, d, 32);
                int   oi = __shfl_xor(i1v, d, 32);
                float o2 = __shfl_xor(m2v, d, 32);
                if (o1 < m1v)      { m2v = fminf(m1v, o2); m1v = o1; i1v = oi; }
                else if (o1 > m1v) { m2v = fminf(m2v, o1); }
                else               { i1v = min(i1v, oi); m2v = m1v; }
            }
            if (cg == 0)
                bis[tg * 8 + i] = (m2v - m1v < MARGIN) ? ~i1v : i1v;
        }
        __syncthreads();

        // ---- exact rescan for flagged tokens (block-uniform) ----
        for (int tok = 0; tok < TOKPB; ++tok) {
            if (bis[tok] >= 0) continue;
            const float* rcol = &A[0][tok];
            float rr2 = exact_rr2_col(rcol);
            float di = exact_dist_col(el + (size_t)tid * CODE_DIM, rcol,
                                      rr2, e2s[tid]);
            float bv = di; int bidx = tid;
            #pragma unroll
            for (int o = 32; o > 0; o >>= 1) {
                float ov = __shfl_down(bv, o, 64);
                int   oi = __shfl_down(bidx, o, 64);
                if (ov < bv || (ov == bv && oi < bidx)) { bv = ov; bidx = oi; }
            }
            if ((tid & 63) == 0) { rtv[tid >> 6] = bv; rti[tid >> 6] = bidx; }
            __syncthreads();
            if (tid == 0) {
                float gv = rtv[0]; int gidx = rti[0];
                #pragma unroll
                for (int w = 1; w < 4; ++w) {
                    if (rtv[w] < gv || (rtv[w] == gv && rti[w] < gidx)) {
                        gv = rtv[w]; gidx = rti[w];
                    }
                }
                bis[tok] = gidx;
            }
            __syncthreads();
        }

        // ---- commit ----
        if (tid < TOKPB) {
            int bi = bis[tid];
            bihist[l][tid] = bi;
            outi[(size_t)(m0 + tid) * N_LAYERS + l] = (float)bi;
            atomicAdd(&cnt[l * NUM_CODE + bi], 1u);
        }

        // ---- residual update + loss: utok=tid&63 (2-way free), part=tid>>6 ----
        {
            int utok = tid & 63, part = tid >> 6;
            int bi = bis[utok];
            const float4* qr = reinterpret_cast<const float4*>(
                el + (size_t)bi * CODE_DIM + part * 32);
            double ls = 0.0;
            #pragma unroll
            for (int q8 = 0; q8 < 8; ++q8) {
                float4 e = qr[q8];
                int k = part * 32 + q8 * 4;
                float r0 = __fsub_rn(A[k + 0][utok], e.x);
                float r1 = __fsub_rn(A[k + 1][utok], e.y);
                float r2 = __fsub_rn(A[k + 2][utok], e.z);
                float r3 = __fsub_rn(A[k + 3][utok], e.w);
                A[k + 0][utok] = r0; A[k + 1][utok] = r1;
                A[k + 2][utok] = r2; A[k + 3][utok] = r3;
                ls = fma((double)r0, (double)r0, ls);
                ls = fma((double)r1, (double)r1, ls);
                ls = fma((double)r2, (double)r2, ls);
                ls = fma((double)r3, (double)r3, ls);
            }
            #pragma unroll
            for (int o = 32; o > 0; o >>= 1)
                ls += __shfl_down(ls, o, 64);
            if ((tid & 63) == 0) lred[tid >> 6] = ls;
        }
        __syncthreads();
        if (tid == 0)
            atomicAdd(&lossws[l], lred[0] + lred[1] + lred[2] + lred[3]);
        __syncthreads();
    }

    // ---------------- Phase B: coalesced quantized output (r11-validated) ----
    float* sq  = &A[0][0];                      // [5][64][9]  11520 B
    float* sx  = sq + 5 * 64 * 9;               // [8][64]      2048 B
    float* sob = sx + 8 * 64;                   // [8][64][5]  10240 B

    for (int nc = 0; nc < 16; ++nc) {
        const int n0 = nc * 8;
        __syncthreads();
        #pragma unroll
        for (int rep = 0; rep < 3; ++rep) {
            int f4 = rep * 256 + tid;            // 640 float4: q slices
            if (f4 < 640) {
                int row = f4 >> 1;               // l*64 + tok
                int half = f4 & 1;
                int l2 = row >> 6, tok = row & 63;
                float4 v = *reinterpret_cast<const float4*>(
                    emb + ((size_t)l2 * NUM_CODE + bihist[l2][tok]) * CODE_DIM
                        + n0 + half * 4);
                float* d = &sq[row * 9 + half * 4];
                d[0] = v.x; d[1] = v.y; d[2] = v.z; d[3] = v.w;
            }
        }
        if (tid < 128) {                         // x slice [8 n][64 tok]
            int np = tid >> 4, tk = (tid & 15) * 4;
            float4 v = *reinterpret_cast<const float4*>(
                x + xbase + (size_t)(n0 + np) * TT + tk);
            *reinterpret_cast<float4*>(&sx[np * 64 + tk]) = v;
        }
        __syncthreads();
        #pragma unroll
        for (int rep = 0; rep < 2; ++rep) {
            int cell = rep * 256 + tid;          // 512 cells
            int np = cell >> 6, tok = cell & 63;
            float xv = sx[np * 64 + tok];
            float rr = xv;
            float* dst = &sob[(np * 64 + tok) * 5];
            #pragma unroll
            for (int l2 = 0; l2 < N_LAYERS; ++l2) {
                rr = __fsub_rn(rr, sq[(l2 * 64 + tok) * 9 + np]);
                dst[l2] = __fsub_rn(xv, rr);
            }
        }
        __syncthreads();
        #pragma unroll
        for (int rep = 0; rep < 3; ++rep) {
            int f4 = rep * 256 + tid;            // 640 float4 out
            if (f4 < 640) {
                int np = f4 / 80, kk = f4 % 80;
                float4 v = *reinterpret_cast<const float4*>(&sob[np * 320 + kk * 4]);
                *reinterpret_cast<float4*>(
                    outq + ((size_t)((size_t)b * CODE_DIM + n0 + np) * TT + t0)
                             * N_LAYERS + kk * 4) = v;
            }
        }
    }
}

__global__ __launch_bounds__(256) void rvq_finalize_kernel(
        const unsigned int* __restrict__ cnt,
        const double* __restrict__ lossws,
        float* __restrict__ out)
{
    __shared__ double sd[256];
    const int k = threadIdx.x;
    const double epsf = 1.1920928955078125e-07;  // float32 eps
    for (int l = 0; l < N_LAYERS; ++l) {
        float p = (float)cnt[l * NUM_CODE + k] / 131072.0f;   // exact (/2^17)
        double term = (double)p * log((double)p + epsf);
        sd[k] = term;
        __syncthreads();
        for (int s = 128; s > 0; s >>= 1) {
            if (k < s) sd[k] += sd[k + s];
            __syncthreads();
        }
        if (k == 0) out[PPLOFF + l] = (float)exp(-sd[0]);
        __syncthreads();
    }
    if (k == 0) {
        double tot = 0.0;
        for (int l = 0; l < N_LAYERS; ++l) tot += lossws[l];
        out[LOSSOFF] = (float)(tot / 16777216.0);   // / (B*N*T)
    }
}

extern "C" void kernel_launch(void* const* d_in, const int* in_sizes, int n_in,
                              void* d_out, int out_size, void* d_ws, size_t ws_size,
                              hipStream_t stream)
{
    const float* x   = (const float*)d_in[0];
    const float* emb = (const float*)d_in[1];
    float* out = (float*)d_out;

    unsigned int* cnt = (unsigned int*)d_ws;
    double* lossws    = (double*)((char*)d_ws + 5120);
    float* ee2ws      = (float*)((char*)d_ws + 5160);

    rvq_init_kernel<<<5, 256, 0, stream>>>(emb, cnt, lossws, ee2ws);
    rvq_main_kernel<<<MTOK / TOKPB, 256, 0, stream>>>(x, emb, out, cnt, lossws, ee2ws);
    rvq_finalize_kernel<<<1, 256, 0, stream>>>(cnt, lossws, out);
}

// Round 14
// 1425.860 us; speedup vs baseline: 4.0753x; 1.0068x over previous
//
#include <hip/hip_runtime.h>
#include <math.h>

#define NUM_CODE 256
#define CODE_DIM 128
#define N_LAYERS 5
#define TT 8192
#define MTOK 131072
#define TOKPB 64
#define MARGIN 1e-4f

#define QOFF   0ull
#define IOFF   83886080ull              // 16*128*8192*5
#define PPLOFF 84541440ull
#define LOSSOFF 84541445ull

// ws: [0,5120) u32 cnt[5][256]; [5120,5160) double loss[5]; [5160,10280) float ee2[5][256]
//
// Numeric model (CONFIRMED r6): dot_c / ee2_c = numpy pairwise-8 mul/add trees;
// dist = fl(fl(rr2+ee2_c) - fl(2*dot_c)); argmin first-min; residual fl32 sub.
// r14 = r13 with software pipelining: double-buffered Bt (1 barrier/chunk,
// global prefetch overlapped with FMA), e2 staged once for all layers,
// float2-packed accumulators (v_pk_fma_f32 candidates). Decisions unchanged:
// fast u-filter + MARGIN-gated bitwise-exact rescan (r11-r13 validated).

__global__ __launch_bounds__(256) void rvq_init_kernel(
        const float* __restrict__ emb,
        unsigned int* __restrict__ cnt,
        double* __restrict__ lossws,
        float* __restrict__ ee2)
{
    int g = blockIdx.x * 256 + threadIdx.x;
    if (g < N_LAYERS) lossws[g] = 0.0;
    if (g < N_LAYERS * NUM_CODE) {
        cnt[g] = 0u;
        const float* e = emb + (size_t)g * CODE_DIM;
        float s[8];
        #pragma unroll
        for (int j = 0; j < 8; ++j) s[j] = __fmul_rn(e[j], e[j]);
        #pragma unroll
        for (int i = 8; i < CODE_DIM; i += 8) {
            #pragma unroll
            for (int j = 0; j < 8; ++j)
                s[j] = __fadd_rn(s[j], __fmul_rn(e[i + j], e[i + j]));
        }
        ee2[g] = __fadd_rn(
            __fadd_rn(__fadd_rn(s[0], s[1]), __fadd_rn(s[2], s[3])),
            __fadd_rn(__fadd_rn(s[4], s[5]), __fadd_rn(s[6], s[7])));
    }
}

// Exact reference dist helpers (r11-r13 validated). rcol = LDS residual column.
__device__ __forceinline__ float exact_rr2_col(const float* __restrict__ rcol)
{
    float s[8];
    #pragma unroll
    for (int i = 0; i < 16; ++i) {
        #pragma unroll
        for (int j = 0; j < 8; ++j) {
            float rv = rcol[(8 * i + j) * TOKPB];
            float p = __fmul_rn(rv, rv);
            s[j] = (i == 0) ? p : __fadd_rn(s[j], p);
        }
    }
    return __fadd_rn(
        __fadd_rn(__fadd_rn(s[0], s[1]), __fadd_rn(s[2], s[3])),
        __fadd_rn(__fadd_rn(s[4], s[5]), __fadd_rn(s[6], s[7])));
}

__device__ __forceinline__ float exact_dist_col(
        const float* __restrict__ erow, const float* __restrict__ rcol,
        float rr2, float ee2c)
{
    float s[8];
    #pragma unroll
    for (int i = 0; i < 16; ++i) {
        const float4* ev = reinterpret_cast<const float4*>(erow + 8 * i);
        float4 e0 = ev[0], e1 = ev[1];
        float p0 = __fmul_rn(rcol[(8*i+0) * TOKPB], e0.x);
        float p1 = __fmul_rn(rcol[(8*i+1) * TOKPB], e0.y);
        float p2 = __fmul_rn(rcol[(8*i+2) * TOKPB], e0.z);
        float p3 = __fmul_rn(rcol[(8*i+3) * TOKPB], e0.w);
        float p4 = __fmul_rn(rcol[(8*i+4) * TOKPB], e1.x);
        float p5 = __fmul_rn(rcol[(8*i+5) * TOKPB], e1.y);
        float p6 = __fmul_rn(rcol[(8*i+6) * TOKPB], e1.z);
        float p7 = __fmul_rn(rcol[(8*i+7) * TOKPB], e1.w);
        if (i == 0) {
            s[0]=p0; s[1]=p1; s[2]=p2; s[3]=p3;
            s[4]=p4; s[5]=p5; s[6]=p6; s[7]=p7;
        } else {
            s[0]=__fadd_rn(s[0],p0); s[1]=__fadd_rn(s[1],p1);
            s[2]=__fadd_rn(s[2],p2); s[3]=__fadd_rn(s[3],p3);
            s[4]=__fadd_rn(s[4],p4); s[5]=__fadd_rn(s[5],p5);
            s[6]=__fadd_rn(s[6],p6); s[7]=__fadd_rn(s[7],p7);
        }
    }
    float dot = __fadd_rn(
        __fadd_rn(__fadd_rn(s[0], s[1]), __fadd_rn(s[2], s[3])),
        __fadd_rn(__fadd_rn(s[4], s[5]), __fadd_rn(s[6], s[7])));
    float t1 = __fadd_rn(rr2, ee2c);
    return __fsub_rn(t1, __fadd_rn(dot, dot));
}

__global__ __launch_bounds__(256) void rvq_main_kernel(
        const float* __restrict__ x,
        const float* __restrict__ emb,
        float* __restrict__ out,
        unsigned int* __restrict__ cnt,
        double* __restrict__ lossws,
        const float* __restrict__ ee2ws)
{
    __shared__ float A[CODE_DIM][TOKPB];        // residual [k][tok]     32 KB
    __shared__ float Bt[2][16][NUM_CODE];       // emb chunk dbuf        32 KB
    __shared__ float e2all[N_LAYERS][NUM_CODE]; // all layers' |e|^2      5 KB
    __shared__ int   bis[TOKPB];
    __shared__ int   bihist[N_LAYERS][TOKPB];
    __shared__ float rtv[4];
    __shared__ int   rti[4];
    __shared__ double lred[4];

    const int tid = threadIdx.x;
    const int m0  = blockIdx.x * TOKPB;
    const int b   = m0 >> 13;
    const int t0  = m0 & (TT - 1);
    const size_t xbase = (size_t)b * (CODE_DIM * (size_t)TT) + t0;

    float* __restrict__ outq = out + QOFF;
    float* __restrict__ outi = out + IOFF;

    // ---- load residual tile A[k][tok] = x; stage all e2 ----
    #pragma unroll
    for (int rep = 0; rep < 8; ++rep) {
        int f4 = rep * 256 + tid;               // 2048 float4
        int k = f4 >> 4;
        int tk = (f4 & 15) * 4;
        float4 v = *reinterpret_cast<const float4*>(x + xbase + (size_t)k * TT + tk);
        *reinterpret_cast<float4*>(&A[k][tk]) = v;
    }
    #pragma unroll
    for (int i = 0; i < N_LAYERS; ++i)
        e2all[i][tid] = ee2ws[i * NUM_CODE + tid];

    const int tg = tid >> 5;                    // token octet 0..7
    const int cg = tid & 31;                    // code slot 0..31
    // thread's codes: pairs (cg*4+0,1),(cg*4+2,3),(128+cg*4+0,1),(128+cg*4+2,3)

    for (int l = 0; l < N_LAYERS; ++l) {
        const float* __restrict__ el = emb + (size_t)l * NUM_CODE * CODE_DIM;

        float2 acc[8][4];
        #pragma unroll
        for (int i = 0; i < 8; ++i)
            #pragma unroll
            for (int j = 0; j < 4; ++j) acc[i][j] = make_float2(0.f, 0.f);

        // ---- prologue: stage chunk 0 into Bt[0] ----
        {
            const float4* ep = reinterpret_cast<const float4*>(
                el + (size_t)tid * CODE_DIM);
            float4 q0 = ep[0], q1 = ep[1], q2 = ep[2], q3 = ep[3];
            Bt[0][ 0][tid]=q0.x; Bt[0][ 1][tid]=q0.y; Bt[0][ 2][tid]=q0.z; Bt[0][ 3][tid]=q0.w;
            Bt[0][ 4][tid]=q1.x; Bt[0][ 5][tid]=q1.y; Bt[0][ 6][tid]=q1.z; Bt[0][ 7][tid]=q1.w;
            Bt[0][ 8][tid]=q2.x; Bt[0][ 9][tid]=q2.y; Bt[0][10][tid]=q2.z; Bt[0][11][tid]=q2.w;
            Bt[0][12][tid]=q3.x; Bt[0][13][tid]=q3.y; Bt[0][14][tid]=q3.z; Bt[0][15][tid]=q3.w;
        }
        __syncthreads();   // also covers A writes (layer 0) / A updates (l>0)

        // ---- pipelined GEMM: 8 chunks, 1 barrier each ----
        for (int kc = 0; kc < 8; ++kc) {
            float4 p0, p1, p2, p3;
            if (kc < 7) {   // prefetch next chunk (latency hides under FMA)
                const float4* ep = reinterpret_cast<const float4*>(
                    el + (size_t)tid * CODE_DIM + (kc + 1) * 16);
                p0 = ep[0]; p1 = ep[1]; p2 = ep[2]; p3 = ep[3];
            }
            const int buf = kc & 1;
            #pragma unroll
            for (int k = 0; k < 16; ++k) {
                float4 a0 = *reinterpret_cast<const float4*>(&A[kc*16 + k][tg*8]);
                float4 a1 = *reinterpret_cast<const float4*>(&A[kc*16 + k][tg*8 + 4]);
                float2 b0 = *reinterpret_cast<const float2*>(&Bt[buf][k][cg*4]);
                float2 b1 = *reinterpret_cast<const float2*>(&Bt[buf][k][cg*4 + 2]);
                float2 b2 = *reinterpret_cast<const float2*>(&Bt[buf][k][128 + cg*4]);
                float2 b3 = *reinterpret_cast<const float2*>(&Bt[buf][k][128 + cg*4 + 2]);
                float av[8] = {a0.x,a0.y,a0.z,a0.w,a1.x,a1.y,a1.z,a1.w};
                #pragma unroll
                for (int i = 0; i < 8; ++i) {
                    acc[i][0].x = fmaf(av[i], b0.x, acc[i][0].x);
                    acc[i][0].y = fmaf(av[i], b0.y, acc[i][0].y);
                    acc[i][1].x = fmaf(av[i], b1.x, acc[i][1].x);
                    acc[i][1].y = fmaf(av[i], b1.y, acc[i][1].y);
                    acc[i][2].x = fmaf(av[i], b2.x, acc[i][2].x);
                    acc[i][2].y = fmaf(av[i], b2.y, acc[i][2].y);
                    acc[i][3].x = fmaf(av[i], b3.x, acc[i][3].x);
                    acc[i][3].y = fmaf(av[i], b3.y, acc[i][3].y);
                }
            }
            if (kc < 7) {   // write prefetched chunk into the other buffer
                const int nb = buf ^ 1;
                Bt[nb][ 0][tid]=p0.x; Bt[nb][ 1][tid]=p0.y; Bt[nb][ 2][tid]=p0.z; Bt[nb][ 3][tid]=p0.w;
                Bt[nb][ 4][tid]=p1.x; Bt[nb][ 5][tid]=p1.y; Bt[nb][ 6][tid]=p1.z; Bt[nb][ 7][tid]=p1.w;
                Bt[nb][ 8][tid]=p2.x; Bt[nb][ 9][tid]=p2.y; Bt[nb][10][tid]=p2.z; Bt[nb][11][tid]=p2.w;
                Bt[nb][12][tid]=p3.x; Bt[nb][13][tid]=p3.y; Bt[nb][14][tid]=p3.z; Bt[nb][15][tid]=p3.w;
            }
            __syncthreads();
        }

        // ---- epilogue: u-space top-2 per token, in-register merge (w=32) ----
        float ee2r[8];
        #pragma unroll
        for (int j = 0; j < 4; ++j) {
            ee2r[j]     = e2all[l][cg * 4 + j];
            ee2r[4 + j] = e2all[l][128 + cg * 4 + j];
        }
        #pragma unroll
        for (int i = 0; i < 8; ++i) {
            float m1v = INFINITY, m2v = INFINITY;
            int i1v = 0;
            #pragma unroll
            for (int j = 0; j < 8; ++j) {
                float dv = (j & 1) ? acc[i][j >> 1].y : acc[i][j >> 1].x;
                float u = __fsub_rn(ee2r[(j >> 1) * 2 + (j & 1) + ((j >= 4) ? 0 : 0)],
                                    __fadd_rn(dv, dv));
                // code index: pairs (cg*4+0,1),(cg*4+2,3),(128+cg*4+0,1),(128+cg*4+2,3)
                int cj = ((j >> 2) ? 128 : 0) + cg * 4 + (j & 3);
                u = __fsub_rn(ee2r[j], __fadd_rn(dv, dv));
                bool b1 = u < m1v, b2 = u < m2v;
                m2v = b1 ? m1v : (b2 ? u : m2v);
                m1v = b1 ? u : m1v;
                i1v = b1 ? cj : i1v;
            }
            #pragma unroll
            for (int d = 1; d < 32; d <<= 1) {
                float o1 = __shfl_xor(m1v, d, 32);
                int   oi = __shfl_xor(i1v, d, 32);
                float o2 = __shfl_xor(m2v, d, 32);
                if (o1 < m1v)      { m2v = fminf(m1v, o2); m1v = o1; i1v = oi; }
                else if (o1 > m1v) { m2v = fminf(m2v, o1); }
                else               { i1v = min(i1v, oi); m2v = m1v; }
            }
            if (cg == 0)
                bis[tg * 8 + i] = (m2v - m1v < MARGIN) ? ~i1v : i1v;
        }
        __syncthreads();

        // ---- exact rescan for flagged tokens (block-uniform) ----
        for (int tok = 0; tok < TOKPB; ++tok) {
            if (bis[tok] >= 0) continue;
            const float* rcol = &A[0][tok];
            float rr2 = exact_rr2_col(rcol);
            float di = exact_dist_col(el + (size_t)tid * CODE_DIM, rcol,
                                      rr2, e2all[l][tid]);
            float bv = di; int bidx = tid;
            #pragma unroll
            for (int o = 32; o > 0; o >>= 1) {
                float ov = __shfl_down(bv, o, 64);
                int   oi = __shfl_down(bidx, o, 64);
                if (ov < bv || (ov == bv && oi < bidx)) { bv = ov; bidx = oi; }
            }
            if ((tid & 63) == 0) { rtv[tid >> 6] = bv; rti[tid >> 6] = bidx; }
            __syncthreads();
            if (tid == 0) {
                float gv = rtv[0]; int gidx = rti[0];
                #pragma unroll
                for (int w = 1; w < 4; ++w) {
                    if (rtv[w] < gv || (rtv[w] == gv && rti[w] < gidx)) {
                        gv = rtv[w]; gidx = rti[w];
                    }
                }
                bis[tok] = gidx;
            }
            __syncthreads();
        }

        // ---- commit ----
        if (tid < TOKPB) {
            int bi = bis[tid];
            bihist[l][tid] = bi;
            outi[(size_t)(m0 + tid) * N_LAYERS + l] = (float)bi;
            atomicAdd(&cnt[l * NUM_CODE + bi], 1u);
        }

        // ---- residual update + loss: utok=tid&63 (2-way free), part=tid>>6 ----
        {
            int utok = tid & 63, part = tid >> 6;
            int bi = bis[utok];
            const float4* qr = reinterpret_cast<const float4*>(
                el + (size_t)bi * CODE_DIM + part * 32);
            double ls = 0.0;
            #pragma unroll
            for (int q8 = 0; q8 < 8; ++q8) {
                float4 e = qr[q8];
                int k = part * 32 + q8 * 4;
                float r0 = __fsub_rn(A[k + 0][utok], e.x);
                float r1 = __fsub_rn(A[k + 1][utok], e.y);
                float r2 = __fsub_rn(A[k + 2][utok], e.z);
                float r3 = __fsub_rn(A[k + 3][utok], e.w);
                A[k + 0][utok] = r0; A[k + 1][utok] = r1;
                A[k + 2][utok] = r2; A[k + 3][utok] = r3;
                ls = fma((double)r0, (double)r0, ls);
                ls = fma((double)r1, (double)r1, ls);
                ls = fma((double)r2, (double)r2, ls);
                ls = fma((double)r3, (double)r3, ls);
            }
            #pragma unroll
            for (int o = 32; o > 0; o >>= 1)
                ls += __shfl_down(ls, o, 64);
            if ((tid & 63) == 0) lred[tid >> 6] = ls;
        }
        __syncthreads();
        if (tid == 0)
            atomicAdd(&lossws[l], lred[0] + lred[1] + lred[2] + lred[3]);
        // next layer's prologue barrier orders A reads after these writes
    }

    // ---------------- Phase B: coalesced quantized output (r11-validated) ----
    __syncthreads();
    float* sq  = &A[0][0];                      // [5][64][9]  11520 B
    float* sx  = sq + 5 * 64 * 9;               // [8][64]      2048 B
    float* sob = sx + 8 * 64;                   // [8][64][5]  10240 B

    for (int nc = 0; nc < 16; ++nc) {
        const int n0 = nc * 8;
        __syncthreads();
        #pragma unroll
        for (int rep = 0; rep < 3; ++rep) {
            int f4 = rep * 256 + tid;            // 640 float4: q slices
            if (f4 < 640) {
                int row = f4 >> 1;               // l*64 + tok
                int half = f4 & 1;
                int l2 = row >> 6, tok = row & 63;
                float4 v = *reinterpret_cast<const float4*>(
                    emb + ((size_t)l2 * NUM_CODE + bihist[l2][tok]) * CODE_DIM
                        + n0 + half * 4);
                float* d = &sq[row * 9 + half * 4];
                d[0] = v.x; d[1] = v.y; d[2] = v.z; d[3] = v.w;
            }
        }
        if (tid < 128) {                         // x slice [8 n][64 tok]
            int np = tid >> 4, tk = (tid & 15) * 4;
            float4 v = *reinterpret_cast<const float4*>(
                x + xbase + (size_t)(n0 + np) * TT + tk);
            *reinterpret_cast<float4*>(&sx[np * 64 + tk]) = v;
        }
        __syncthreads();
        #pragma unroll
        for (int rep = 0; rep < 2; ++rep) {
            int cell = rep * 256 + tid;          // 512 cells
            int np = cell >> 6, tok = cell & 63;
            float xv = sx[np * 64 + tok];
            float rr = xv;
            float* dst = &sob[(np * 64 + tok) * 5];
            #pragma unroll
            for (int l2 = 0; l2 < N_LAYERS; ++l2) {
                rr = __fsub_rn(rr, sq[(l2 * 64 + tok) * 9 + np]);
                dst[l2] = __fsub_rn(xv, rr);
            }
        }
        __syncthreads();
        #pragma unroll
        for (int rep = 0; rep < 3; ++rep) {
            int f4 = rep * 256 + tid;            // 640 float4 out
            if (f4 < 640) {
                int np = f4 / 80, kk = f4 % 80;
                float4 v = *reinterpret_cast<const float4*>(&sob[np * 320 + kk * 4]);
                *reinterpret_cast<float4*>(
                    outq + ((size_t)((size_t)b * CODE_DIM + n0 + np) * TT + t0)
                             * N_LAYERS + kk * 4) = v;
            }
        }
    }
}

__global__ __launch_bounds__(256) void rvq_finalize_kernel(
        const unsigned int* __restrict__ cnt,
        const double* __restrict__ lossws,
        float* __restrict__ out)
{
    __shared__ double sd[256];
    const int k = threadIdx.x;
    const double epsf = 1.1920928955078125e-07;  // float32 eps
    for (int l = 0; l < N_LAYERS; ++l) {
        float p = (float)cnt[l * NUM_CODE + k] / 131072.0f;   // exact (/2^17)
        double term = (double)p * log((double)p + epsf);
        sd[k] = term;
        __syncthreads();
        for (int s = 128; s > 0; s >>= 1) {
            if (k < s) sd[k] += sd[k + s];
            __syncthreads();
        }
        if (k == 0) out[PPLOFF + l] = (float)exp(-sd[0]);
        __syncthreads();
    }
    if (k == 0) {
        double tot = 0.0;
        for (int l = 0; l < N_LAYERS; ++l) tot += lossws[l];
        out[LOSSOFF] = (float)(tot / 16777216.0);   // / (B*N*T)
    }
}

extern "C" void kernel_launch(void* const* d_in, const int* in_sizes, int n_in,
                              void* d_out, int out_size, void* d_ws, size_t ws_size,
                              hipStream_t stream)
{
    const float* x   = (const float*)d_in[0];
    const float* emb = (const float*)d_in[1];
    float* out = (float*)d_out;

    unsigned int* cnt = (unsigned int*)d_ws;
    double* lossws    = (double*)((char*)d_ws + 5120);
    float* ee2ws      = (float*)((char*)d_ws + 5160);

    rvq_init_kernel<<<5, 256, 0, stream>>>(emb, cnt, lossws, ee2ws);
    rvq_main_kernel<<<MTOK / TOKPB, 256, 0, stream>>>(x, emb, out, cnt, lossws, ee2ws);
    rvq_finalize_kernel<<<1, 256, 0, stream>>>(cnt, lossws, out);
}